// Round 10
// baseline (520.391 us; speedup 1.0000x reference)
//
#include <hip/hip_runtime.h>

// RBM CD-1 step on MI355X — round 18.
// = round-17 kernel (verified 492.3us, best) + MFMA shape switch
// 16x16x32 -> 32x32x16 in ALL GEMM main loops (gemm256, g23_k).
// Rationale: main loop is MFMA-retire-bound; 32x32x16 retires 4060 FLOP/cyc/CU
// (m119) vs 3376 for 16x16x32 (m06) -> -17% on the binding term.
// LDS layout/staging/granule-swizzle BYTE-IDENTICAL; new fragment reads are
// conflict-free under the existing swizzle (quad (4r+slot)%8 uniform, 8 hits
// each). Fragments: A row=lane&31 k=8*(lane>>5)+j (+2s per K-step);
// C/D (m74/m101): col=lane&31, row=(reg&3)+8*(reg>>2)+4*(lane>>5).
// acc = f32x16[4 m-tiles][2 n-tiles]. All epilogues remapped accordingly.
// Pipeline (2 phases/K-tile, counted vmcnt 8/4/0) identical to r17.

typedef unsigned short u16;
typedef short s16x8 __attribute__((ext_vector_type(8)));
typedef float f32x4 __attribute__((ext_vector_type(4)));
typedef float f32x16 __attribute__((ext_vector_type(16)));
typedef u16 u16x4 __attribute__((ext_vector_type(4)));
typedef u16 u16x8 __attribute__((ext_vector_type(8)));

constexpr int Bn = 8192, Vn = 2048, Hn = 1024;
constexpr size_t VH = (size_t)Vn * Hn;
constexpr size_t BH = (size_t)Bn * Hn;
constexpr size_t OUT_RECON = BH;                        // 8388608
constexpr size_t OUT_WGRAD = OUT_RECON + 1;             // 8388609
constexpr size_t OUT_VBG   = OUT_WGRAD + VH;            // 10485761
constexpr size_t OUT_HBG   = OUT_VBG + Vn;              // 10487809

__device__ __forceinline__ u16 f2bf(float x) {
  union { float f; unsigned u; } a; a.f = x;
  unsigned r = a.u + 0x7FFFu + ((a.u >> 16) & 1u);   // RNE
  return (u16)(r >> 16);
}
__device__ __forceinline__ float bf2f(u16 h) {
  union { unsigned u; float f; } a; a.u = ((unsigned)h) << 16;
  return a.f;
}
__device__ __forceinline__ float sigmoidf_(float x) {
  return 1.0f / (1.0f + __expf(-x));
}

using gptr_t = const unsigned int __attribute__((address_space(1)))*;
using lptr_t = unsigned int __attribute__((address_space(3)))*;

__device__ __forceinline__ void gload16(const u16* g, u16* l) {
  __builtin_amdgcn_global_load_lds((gptr_t)(unsigned long long)g,
                                   (lptr_t)(unsigned long long)l, 16, 0, 0);
}

// ---------------- merged prep kernel ----------------
// blocks [0,4096): v[B,V] f32 -> v_cat[B,2V]=[hi|lo], vT[V,B], vbd partials.
// blocks [4096,4608): w[V,H] f32 -> w_cat[V,2H], wT_cat[H,2V].
__global__ void prep_all_k(const float* __restrict__ v, u16* __restrict__ vcat,
                           u16* __restrict__ vT, float* __restrict__ vbd_p,
                           const float* __restrict__ w, u16* __restrict__ w_cat,
                           u16* __restrict__ wTc) {
  __shared__ u16 tile16[64][68];
  __shared__ float cs[16][64];
  __shared__ float tile32[64][65];
  const int bx = blockIdx.x;
  const int t = threadIdx.x;
  if (bx < 4096) {
    const int b0 = (bx & 127) << 6, c0 = (bx >> 7) << 6;
    const int rg = t >> 4;          // 0..15 row group
    const int cg = (t & 15) << 2;   // col *4
    float ca[4] = {0.f, 0.f, 0.f, 0.f};
#pragma unroll
    for (int i = 0; i < 4; ++i) {
      int r = rg + 16 * i;
      f32x4 x = *(const f32x4*)&v[(size_t)(b0 + r) * Vn + c0 + cg];
      u16x4 hi, lo;
#pragma unroll
      for (int j = 0; j < 4; ++j) {
        hi[j] = f2bf(x[j]);
        lo[j] = f2bf(x[j] - bf2f(hi[j]));
        tile16[r][cg + j] = hi[j];
        ca[j] += x[j];
      }
      *(u16x4*)&vcat[(size_t)(b0 + r) * (2 * Vn) + c0 + cg] = hi;
      *(u16x4*)&vcat[(size_t)(b0 + r) * (2 * Vn) + Vn + c0 + cg] = lo;
    }
#pragma unroll
    for (int j = 0; j < 4; ++j) cs[rg][cg + j] = ca[j];
    __syncthreads();
    if (t < 64) {
      float s = 0.f;
#pragma unroll
      for (int k = 0; k < 16; ++k) s += cs[k][t];
      vbd_p[(size_t)(bx & 127) * Vn + c0 + t] = s;   // [128][2048]
    }
#pragma unroll
    for (int s2 = 0; s2 < 2; ++s2) {
      int c = t >> 2;
      int seg = (t & 3) + 4 * s2;
      u16x8 pk;
#pragma unroll
      for (int i = 0; i < 8; ++i) pk[i] = tile16[seg * 8 + i][c];
      *(u16x8*)&vT[(size_t)(c0 + c) * Bn + b0 + seg * 8] = pk;
    }
  } else {
    const int wb = bx - 4096;
    const int v0 = (wb & 31) << 6, h0 = (wb >> 5) << 6;
    const int c = t & 63, r = t >> 6;
    for (int rr = r; rr < 64; rr += 4) {
      float x = w[(size_t)(v0 + rr) * Hn + h0 + c];
      tile32[rr][c] = x;
      u16 hi = f2bf(x), lo = f2bf(x - bf2f(hi));
      w_cat[(size_t)(v0 + rr) * (2 * Hn) + h0 + c]      = hi;
      w_cat[(size_t)(v0 + rr) * (2 * Hn) + Hn + h0 + c] = lo;
    }
    __syncthreads();
    for (int rr = r; rr < 64; rr += 4) {
      float x = tile32[c][rr];  // = w[v0+c][h0+rr]
      u16 hi = f2bf(x), lo = f2bf(x - bf2f(hi));
      size_t ro = (size_t)(h0 + rr) * (2 * Vn);
      wTc[ro + v0 + c]      = hi;
      wTc[ro + Vn + v0 + c] = lo;
    }
  }
}

// ---- sampling epilogue for split-K [B,H] pre-activations ----------------
template <int M>
__global__ void epi_h_k(const float* __restrict__ p0, const float* __restrict__ p1,
                        const float* __restrict__ bias, const float* __restrict__ uni,
                        float* __restrict__ f32out, u16* __restrict__ hp_out,
                        u16* __restrict__ hbin_out, u16* __restrict__ tout,
                        float* __restrict__ colp) {
  __shared__ u16 tile[64][68];
  __shared__ float cs[16][64];
  const int b0 = blockIdx.x * 64, c0 = blockIdx.y * 64;
  const int t = threadIdx.x;
  const int rg = t >> 4, cg = (t & 15) << 2;
  float ca[4] = {0.f, 0.f, 0.f, 0.f};
#pragma unroll
  for (int i = 0; i < 4; ++i) {
    int r = rg + 16 * i;
    size_t e = (size_t)(b0 + r) * Hn + c0 + cg;
    f32x4 a = *(const f32x4*)&p0[e];
    f32x4 b = *(const f32x4*)&p1[e];
    f32x4 uu = *(const f32x4*)&uni[e];
    f32x4 hpv;
    u16x4 hb16, qv;
#pragma unroll
    for (int j = 0; j < 4; ++j) {
      float hp = sigmoidf_(a[j] + b[j] + bias[c0 + cg + j]);
      u16 qb = (hp > uu[j]) ? (u16)0x3F80 : (u16)0;
      tile[r][cg + j] = qb;
      if constexpr (M == 1) {
        hpv[j] = hp; hb16[j] = f2bf(hp); qv[j] = qb;
        ca[j] += hp;
      } else {
        ca[j] += (qb ? 1.f : 0.f);
      }
    }
    if constexpr (M == 1) {
      *(f32x4*)&f32out[e] = hpv;        // h_prediction (overwrites p0 region)
      *(u16x4*)&hp_out[e] = hb16;
      *(u16x4*)&hbin_out[e] = qv;
    }
  }
#pragma unroll
  for (int j = 0; j < 4; ++j) cs[rg][cg + j] = ca[j];
  __syncthreads();
  if (t < 64) {
    float s = 0.f;
#pragma unroll
    for (int k = 0; k < 16; ++k) s += cs[k][t];
    colp[(size_t)blockIdx.x * Hn + c0 + t] = s;   // [128][1024]
  }
#pragma unroll
  for (int s2 = 0; s2 < 2; ++s2) {
    int c = t >> 2;
    int seg = (t & 3) + 4 * s2;
    u16x8 pk;
#pragma unroll
    for (int i = 0; i < 8; ++i) pk[i] = tile[seg * 8 + i][c];
    *(u16x8*)&tout[(size_t)(c0 + c) * Bn + b0 + seg * 8] = pk;
  }
}

// ---------------- GEMM 256x256, BK=32, 8 waves, 2-phase, MFMA 32x32x16 ----
// MODE 1: G1 split-K x2 partial (A remap [hi|hi|lo], B remap [hi|lo|hi]).
// MODE 3: split-K x8 grad (G6): A,B += z*K cols -> (z<4?f32out:redp)+(z&3)*VH.
// MODE 4: G4 vk: A=hbin (dup), B=w_cat, K=2048 -> vk, vkT, vbm (fused).
// MODE 5: G5 split-K x2 partial: A=vk (dup), B=wT_cat.
template <int MODE>
__global__ __launch_bounds__(512) void gemm256(
    const u16* __restrict__ A, int lda, const u16* __restrict__ Bm, int ldb, int K,
    const float* __restrict__ bias, const float* __restrict__ uni,
    const float* __restrict__ aux, float* __restrict__ f32out,
    u16* __restrict__ bfout, const u16* __restrict__ aux16,
    float* __restrict__ redp, u16* __restrict__ tout, float* __restrict__ colp) {
  constexpr bool TRANS = (MODE == 4);
  // As[4][256][32] at 0 (32768 u16), Bs[4][256][32] at 32768; 128 KB.
  // MODE4 epilogue ebuf [256][264] (67584 u16 = 132 KB) aliases everything.
  __shared__ __align__(16) u16 smem[TRANS ? 67584 : 65536];
  const int t = threadIdx.x;
  const int lane = t & 63, wave = t >> 6;                // 8 waves
  const int wr = (wave >> 2) << 7;                       // 0 / 128
  const int wc = (wave & 3) << 6;                        // 0/64/128/192
  // MODE-3-only XCD swizzle: grid (8,4,8), z = K-slice. HW: XCD = linear%8
  // (confirmed r12). Remap so XCD k owns z-slice k's full 8x4 MxN grid.
  int bidx = blockIdx.x, bidy = blockIdx.y, bidz = blockIdx.z;
  if constexpr (MODE == 3) {
    const int orig = blockIdx.x + (blockIdx.y << 3) + (blockIdx.z << 5);
    bidz = orig & 7;
    const int r = orig >> 3;       // 0..31 rank within XCD
    bidx = r & 7;
    bidy = r >> 3;
  }
  const int bm = bidx << 8, bn = bidy << 8;
  int kbeg = 0;
  float* pout = f32out;
  if constexpr (MODE == 1 || MODE == 5) {
    kbeg = bidz * K;
    pout = (bidz == 0) ? f32out : redp;
  }
  if constexpr (MODE == 3) {
    size_t off = (size_t)bidz * (size_t)K;
    A += off;
    Bm += off;
    pout = ((bidz < 4) ? f32out : redp) + (size_t)(bidz & 3) * VH;
  }
  f32x16 acc[4][2] = {};
  // staging (one gload = 512 thr x 16B = 128 rows x 64B): LDS row sr = t>>2,
  // granule t&3; fetch SWIZZLED global granule (t&3) ^ ((row>>1)&3) [r5 T2].
  const int sr = t >> 2;
  const int sc = (((t & 3) ^ ((t >> 3) & 3)) << 3);
  const u16* Ag  = A  + (size_t)(bm + sr) * lda + sc;
  const u16* Ag2 = Ag + (size_t)128 * lda;
  const u16* Bg  = Bm + (size_t)(bn + sr) * ldb + sc;
  const u16* Bg2 = Bg + (size_t)128 * ldb;
  // 32x32x16 fragments: row/col = lane&31; k-granule = (lane>>5) + 2*step.
  // Physical slot = kg ^ ((row>>1)&3)  [same swizzle as staging] — conflict-
  // free: quad (4*row+slot)%8 hit exactly 8x per wave-read.
  const int fr32 = lane & 31, hb = lane >> 5;
  const int ga0 = ((hb ^ ((fr32 >> 1) & 3)) << 3);       // K-step 0
  const int ga1 = ga0 ^ 16;                              // K-step 1 (kg^2)

  auto acolf = [&](int k0) -> int {
    if constexpr (MODE == 1)      return (k0 < 2048) ? k0 : k0 - 2048;  // [hi|hi|lo]
    else if constexpr (MODE == 4) return k0 & 1023;
    else if constexpr (MODE == 5) return k0 & 2047;
    else                          return k0;
  };
  auto bcolf = [&](int k0) -> int {
    if constexpr (MODE == 1) return (k0 < 4096) ? k0 : k0 - 4096;       // [hi|lo|hi]
    else                     return k0;
  };
  auto stageA = [&](int kt) {
    const int k0 = kbeg + (kt << 5);
    const int acol = acolf(k0);
    u16* ad = smem + (kt & 3) * 8192 + wave * 512;       // wave-uniform base
    gload16(Ag + acol, ad);
    gload16(Ag2 + acol, ad + 4096);
  };
  auto stageB = [&](int kt) {
    const int k0 = kbeg + (kt << 5);
    const int bcol = bcolf(k0);
    u16* bd = smem + 32768 + (kt & 3) * 8192 + wave * 512;
    gload16(Bg + bcol, bd);
    gload16(Bg2 + bcol, bd + 4096);
  };
  // MODE 4 epilogue-tile L2 prefetch: one probe per 128B L2 line;
  // uni f32 [256][256] tile = 2048 lines = 4 chunks x 512 thr.
  auto pfl4 = [&](int ci) -> float {
    const int L = (ci << 9) + t;         // 0..2047
    return uni[(size_t)(bm + (L >> 3)) * Vn + bn + ((L & 7) << 5)];
  };

  // 2-phase-per-tile counted pipeline (depth-4 slabs, pb = kt&3):
  // steady outstanding at phase-B vmcnt = 12 -> vmcnt(8) guards tile kt+1.
  const int NT = K >> 5;               // >= 32 for all modes
  const int pfbeg = NT - 8;            // probes at kt in [NT-8, NT-4)
  stageA(0); stageB(0); stageA(1); stageB(1); stageA(2); stageB(2);
  asm volatile("s_waitcnt vmcnt(8)" ::: "memory");
  __builtin_amdgcn_s_barrier();
  asm volatile("" ::: "memory");
  s16x8 bf0, bf1, af[4];
  for (int kt = 0; kt < NT; ++kt) {
    const int pb = kt & 3;
    const u16* Ab = smem + pb * 8192;
    const u16* Bb = smem + 32768 + pb * 8192;
    const bool st = (kt < NT - 3);
    // ---- phase A (K-step 0): reads + A-stage + barrier + 8 MFMA ----
    bf0 = *(const s16x8*)&Bb[(wc + fr32) * 32 + ga0];
    bf1 = *(const s16x8*)&Bb[(wc + 32 + fr32) * 32 + ga0];
#pragma unroll
    for (int mt = 0; mt < 4; ++mt)
      af[mt] = *(const s16x8*)&Ab[(wr + mt * 32 + fr32) * 32 + ga0];
    if (st) stageA(kt + 3);
    if constexpr (MODE == 4) {
      if (kt >= pfbeg && kt < pfbeg + 4) {
        float pfv = pfl4(kt - pfbeg);
        asm volatile("" :: "v"(pfv));
      }
    }
    __builtin_amdgcn_s_barrier();
    asm volatile("" ::: "memory");
    __builtin_amdgcn_s_setprio(1);
#pragma unroll
    for (int mt = 0; mt < 4; ++mt) {
      acc[mt][0] = __builtin_amdgcn_mfma_f32_32x32x16_bf16(af[mt], bf0, acc[mt][0], 0, 0, 0);
      acc[mt][1] = __builtin_amdgcn_mfma_f32_32x32x16_bf16(af[mt], bf1, acc[mt][1], 0, 0, 0);
    }
    __builtin_amdgcn_s_setprio(0);
    // ---- phase B (K-step 1): reads + B-stage + vmcnt + barrier + 8 MFMA ----
    bf0 = *(const s16x8*)&Bb[(wc + fr32) * 32 + ga1];
    bf1 = *(const s16x8*)&Bb[(wc + 32 + fr32) * 32 + ga1];
#pragma unroll
    for (int mt = 0; mt < 4; ++mt)
      af[mt] = *(const s16x8*)&Ab[(wr + mt * 32 + fr32) * 32 + ga1];
    if (st) stageB(kt + 3);
    if (kt < NT - 3) {
      asm volatile("s_waitcnt vmcnt(8)" ::: "memory");
    } else if (kt == NT - 3) {
      asm volatile("s_waitcnt vmcnt(4)" ::: "memory");
    } else if (kt == NT - 2) {
      asm volatile("s_waitcnt vmcnt(0)" ::: "memory");
    }
    __builtin_amdgcn_s_barrier();
    asm volatile("" ::: "memory");
    __builtin_amdgcn_s_setprio(1);
#pragma unroll
    for (int mt = 0; mt < 4; ++mt) {
      acc[mt][0] = __builtin_amdgcn_mfma_f32_32x32x16_bf16(af[mt], bf0, acc[mt][0], 0, 0, 0);
      acc[mt][1] = __builtin_amdgcn_mfma_f32_32x32x16_bf16(af[mt], bf1, acc[mt][1], 0, 0, 0);
    }
    __builtin_amdgcn_s_setprio(0);
  }

  // ---- epilogue ----  C/D: col = wc+nt*32+fr32, row = wr+mt*32+(reg&3)+8*(reg>>2)+4*hb
  constexpr int NC = (MODE == 4) ? Vn : Hn;

  if constexpr (MODE == 1 || MODE == 3 || MODE == 5) {
#pragma unroll
    for (int mt = 0; mt < 4; ++mt)
#pragma unroll
      for (int nt = 0; nt < 2; ++nt)
#pragma unroll
        for (int reg = 0; reg < 16; ++reg) {
          int rl = wr + mt * 32 + (reg & 3) + 8 * (reg >> 2) + 4 * hb;
          int cl = wc + nt * 32 + fr32;
          pout[(size_t)(bm + rl) * NC + bn + cl] = acc[mt][nt][reg];
        }
  }

  if constexpr (MODE == 4) {
    __syncthreads();   // all waves done with dbuf before ebuf writes
    float bcol[2];
#pragma unroll
    for (int nt = 0; nt < 2; ++nt) bcol[nt] = bias[bn + wc + nt * 32 + fr32];
    float ux[8][4];
    // chunk ci -> (mt=ci>>3, nt=(ci>>2)&1, q=ci&3); rows e0+j*NC, j=0..3
    auto ld4 = [&](int ci, float* dst) {
      size_t e0 = (size_t)(bm + wr + 4 * hb + ((ci >> 3) << 5) + ((ci & 3) << 3)) * NC
                + (bn + wc + (((ci >> 2) & 1) << 5) + fr32);
      dst[0] = uni[e0];          dst[1] = uni[e0 + NC];
      dst[2] = uni[e0 + 2 * NC]; dst[3] = uni[e0 + 3 * NC];
    };
#pragma unroll
    for (int ci = 0; ci < 8; ++ci) ld4(ci, ux[ci]);
#pragma unroll
    for (int mt = 0; mt < 4; ++mt)
#pragma unroll
      for (int nt = 0; nt < 2; ++nt)
#pragma unroll
        for (int reg = 0; reg < 16; ++reg)
          acc[mt][nt][reg] = sigmoidf_(acc[mt][nt][reg] + bcol[nt]);
    float csum[2] = {0.f, 0.f};
#pragma unroll
    for (int ci = 0; ci < 32; ++ci) {
      const int mt = ci >> 3, nt = (ci >> 2) & 1, q = ci & 3;
      const int rlb = wr + mt * 32 + 8 * q + 4 * hb;
      const int cl = wc + nt * 32 + fr32;
#pragma unroll
      for (int j = 0; j < 4; ++j) {
        u16 qb = (acc[mt][nt][q * 4 + j] > ux[ci & 7][j]) ? (u16)0x3F80 : (u16)0;
        smem[(rlb + j) * 264 + cl] = qb;         // ebuf (feeds vk AND vkT)
        csum[nt] += (qb ? 1.f : 0.f);
      }
      if (ci < 24) ld4(ci + 8, ux[ci & 7]);
    }
    // vbm partials: lanes l and l+32 cover complementary row halves, same col
#pragma unroll
    for (int nt = 0; nt < 2; ++nt) {
      float s = csum[nt];
      s += __shfl_xor(s, 32);
      if (hb == 0)
        colp[(size_t)(blockIdx.x * 2 + (wr >> 7)) * NC + (bn + wc + nt * 32 + fr32)] = s;
    }
    __syncthreads();   // ebuf fully written
    // vk row-major writeout: coalesced u16x8 from ebuf. 256 rows x 32
    // col-chunks = 8192 tasks / 512 thr; consecutive threads fill one row.
#pragma unroll
    for (int it = 0; it < 16; ++it) {
      int id = t + (it << 9);
      int r = id >> 5;                   // 0..255
      int c0 = (id & 31) << 3;           // 0..248
      u16x8 pk = *(const u16x8*)&smem[r * 264 + c0];
      *(u16x8*)&bfout[(size_t)(bm + r) * NC + bn + c0] = pk;
    }
    // transposed write-out, 64B-contiguous per thread: thread owns
    // (col c, 32-row span q*32); 4x u16x8 stores land in ONE 64B line.
#pragma unroll
    for (int it = 0; it < 4; ++it) {
      int id = t + (it << 9);
      int c = id & 255;
      int q = id >> 8;                   // 0..7
#pragma unroll
      for (int i8 = 0; i8 < 4; ++i8) {
        u16x8 pk;
#pragma unroll
        for (int i2 = 0; i2 < 8; ++i2)
          pk[i2] = smem[(q * 32 + i8 * 8 + i2) * 264 + c];
        *(u16x8*)&tout[(size_t)(bn + c) * Bn + bm + q * 32 + i8 * 8] = pk;
      }
    }
  }
}

// ---------------- merged G2+G3 (512 blocks, one launch) -------------------
// flat < 256:  G2 recon. A=h_p[B,H], B=w_cat hi, K=1024, NC=2048;
//              epilogue: sigmoid + |v_hi - vp| partial -> redp2[bidy*32+bidx].
// flat >= 256: G3 grad. A=vT+z*1024, B=hT+z*1024 (ld=Bn), K=1024, NC=1024;
//              z-slice XCD swizzle (flat%8 preserved: 256 == 0 mod 8).
__global__ __launch_bounds__(512) void g23_k(
    const u16* __restrict__ A2, const u16* __restrict__ B2,
    const u16* __restrict__ aux16, const float* __restrict__ bias2,
    float* __restrict__ redp2,
    const u16* __restrict__ A3, const u16* __restrict__ B3,
    float* __restrict__ out30, float* __restrict__ out34) {
  __shared__ __align__(16) u16 smem[65536];
  const int t = threadIdx.x;
  const int lane = t & 63, wave = t >> 6;
  const int wr = (wave >> 2) << 7;
  const int wc = (wave & 3) << 6;
  const int flat = blockIdx.x;
  const bool isG2 = (flat < 256);
  int bidx, bidy, bidz = 0;
  const u16 *Abase, *Bbase;
  int lda, ldb;
  if (isG2) {
    bidx = flat & 31; bidy = flat >> 5;
    Abase = A2; Bbase = B2; lda = Hn; ldb = 2 * Hn;
  } else {
    const int orig = flat - 256;
    bidz = orig & 7;
    const int rr = orig >> 3;          // 0..31 rank within XCD
    bidx = rr & 7; bidy = rr >> 3;
    Abase = A3 + (size_t)bidz * 1024;
    Bbase = B3 + (size_t)bidz * 1024;
    lda = Bn; ldb = Bn;
  }
  const int bm = bidx << 8, bn = bidy << 8;
  f32x16 acc[4][2] = {};
  const int sr = t >> 2;
  const int sc = (((t & 3) ^ ((t >> 3) & 3)) << 3);
  const u16* Ag  = Abase + (size_t)(bm + sr) * lda + sc;
  const u16* Ag2 = Ag + (size_t)128 * lda;
  const u16* Bg  = Bbase + (size_t)(bn + sr) * ldb + sc;
  const u16* Bg2 = Bg + (size_t)128 * ldb;
  const int fr32 = lane & 31, hb = lane >> 5;
  const int ga0 = ((hb ^ ((fr32 >> 1) & 3)) << 3);
  const int ga1 = ga0 ^ 16;

  auto stageA = [&](int kt) {
    u16* ad = smem + (kt & 3) * 8192 + wave * 512;
    gload16(Ag + (kt << 5), ad);
    gload16(Ag2 + (kt << 5), ad + 4096);
  };
  auto stageB = [&](int kt) {
    u16* bd = smem + 32768 + (kt & 3) * 8192 + wave * 512;
    gload16(Bg + (kt << 5), bd);
    gload16(Bg2 + (kt << 5), bd + 4096);
  };
  auto pfl2 = [&](int ci) -> unsigned {
    const int L = (ci << 9) + t;         // 0..1023
    return (unsigned)aux16[(size_t)(bm + (L >> 2)) * 4096 + bn + ((L & 3) << 6)];
  };

  constexpr int NT = 32;
  stageA(0); stageB(0); stageA(1); stageB(1); stageA(2); stageB(2);
  asm volatile("s_waitcnt vmcnt(8)" ::: "memory");
  __builtin_amdgcn_s_barrier();
  asm volatile("" ::: "memory");
  s16x8 bf0, bf1, af[4];
  for (int kt = 0; kt < NT; ++kt) {
    const int pb = kt & 3;
    const u16* Ab = smem + pb * 8192;
    const u16* Bb = smem + 32768 + pb * 8192;
    const bool st = (kt < NT - 3);
    // phase A
    bf0 = *(const s16x8*)&Bb[(wc + fr32) * 32 + ga0];
    bf1 = *(const s16x8*)&Bb[(wc + 32 + fr32) * 32 + ga0];
#pragma unroll
    for (int mt = 0; mt < 4; ++mt)
      af[mt] = *(const s16x8*)&Ab[(wr + mt * 32 + fr32) * 32 + ga0];
    if (st) stageA(kt + 3);
    if (isG2 && kt >= NT - 8 && kt < NT - 6) {
      unsigned pfv = pfl2(kt - (NT - 8));
      asm volatile("" :: "v"(pfv));
    }
    __builtin_amdgcn_s_barrier();
    asm volatile("" ::: "memory");
    __builtin_amdgcn_s_setprio(1);
#pragma unroll
    for (int mt = 0; mt < 4; ++mt) {
      acc[mt][0] = __builtin_amdgcn_mfma_f32_32x32x16_bf16(af[mt], bf0, acc[mt][0], 0, 0, 0);
      acc[mt][1] = __builtin_amdgcn_mfma_f32_32x32x16_bf16(af[mt], bf1, acc[mt][1], 0, 0, 0);
    }
    __builtin_amdgcn_s_setprio(0);
    // phase B
    bf0 = *(const s16x8*)&Bb[(wc + fr32) * 32 + ga1];
    bf1 = *(const s16x8*)&Bb[(wc + 32 + fr32) * 32 + ga1];
#pragma unroll
    for (int mt = 0; mt < 4; ++mt)
      af[mt] = *(const s16x8*)&Ab[(wr + mt * 32 + fr32) * 32 + ga1];
    if (st) stageB(kt + 3);
    if (kt < NT - 3) {
      asm volatile("s_waitcnt vmcnt(8)" ::: "memory");
    } else if (kt == NT - 3) {
      asm volatile("s_waitcnt vmcnt(4)" ::: "memory");
    } else if (kt == NT - 2) {
      asm volatile("s_waitcnt vmcnt(0)" ::: "memory");
    }
    __builtin_amdgcn_s_barrier();
    asm volatile("" ::: "memory");
    __builtin_amdgcn_s_setprio(1);
#pragma unroll
    for (int mt = 0; mt < 4; ++mt) {
      acc[mt][0] = __builtin_amdgcn_mfma_f32_32x32x16_bf16(af[mt], bf0, acc[mt][0], 0, 0, 0);
      acc[mt][1] = __builtin_amdgcn_mfma_f32_32x32x16_bf16(af[mt], bf1, acc[mt][1], 0, 0, 0);
    }
    __builtin_amdgcn_s_setprio(0);
  }

  if (isG2) {
    // pipelined recon vs v_cat-hi (u16, stride 4096), depth-8 window (&7).
    float bcol[2];
#pragma unroll
    for (int nt = 0; nt < 2; ++nt) bcol[nt] = bias2[bn + wc + nt * 32 + fr32];
    float ax[8][4];
    auto ld4 = [&](int ci, float* dst) {
      size_t e0 = (size_t)(bm + wr + 4 * hb + ((ci >> 3) << 5) + ((ci & 3) << 3)) * 4096
                + (bn + wc + (((ci >> 2) & 1) << 5) + fr32);
      dst[0] = bf2f(aux16[e0]);            dst[1] = bf2f(aux16[e0 + 4096]);
      dst[2] = bf2f(aux16[e0 + 2 * 4096]); dst[3] = bf2f(aux16[e0 + 3 * 4096]);
    };
#pragma unroll
    for (int ci = 0; ci < 8; ++ci) ld4(ci, ax[ci]);
#pragma unroll
    for (int mt = 0; mt < 4; ++mt)
#pragma unroll
      for (int nt = 0; nt < 2; ++nt)
#pragma unroll
        for (int reg = 0; reg < 16; ++reg)
          acc[mt][nt][reg] = sigmoidf_(acc[mt][nt][reg] + bcol[nt]);
    float lsum = 0.f;
#pragma unroll
    for (int ci = 0; ci < 32; ++ci) {
      const int mt = ci >> 3, nt = (ci >> 2) & 1, q = ci & 3;
#pragma unroll
      for (int j = 0; j < 4; ++j) lsum += fabsf(ax[ci & 7][j] - acc[mt][nt][q * 4 + j]);
      if (ci < 24) ld4(ci + 8, ax[ci & 7]);
    }
#pragma unroll
    for (int off = 32; off > 0; off >>= 1) lsum += __shfl_down(lsum, off);
    __syncthreads();
    float* redlds = (float*)smem;
    if (lane == 0) redlds[wave] = lsum;
    __syncthreads();
    if (t == 0) {
      float s = 0.f;
#pragma unroll
      for (int wv = 0; wv < 8; ++wv) s += redlds[wv];
      redp2[(size_t)bidy * 32 + bidx] = s;
    }
  } else {
    float* pout = ((bidz < 4) ? out30 : out34) + (size_t)(bidz & 3) * VH;
#pragma unroll
    for (int mt = 0; mt < 4; ++mt)
#pragma unroll
      for (int nt = 0; nt < 2; ++nt)
#pragma unroll
        for (int reg = 0; reg < 16; ++reg) {
          int rl = wr + mt * 32 + (reg & 3) + 8 * (reg >> 2) + 4 * hb;
          int cl = wc + nt * 32 + fr32;
          pout[(size_t)(bm + rl) * Hn + bn + cl] = acc[mt][nt][reg];
        }
  }
}

// out[i] = sum_{z<8} p[z][i]  (scalar stores: out base misaligned)
__global__ void reduce8_k(const float* __restrict__ p, float* __restrict__ out) {
  size_t e = ((size_t)blockIdx.x * 256 + threadIdx.x) * 4;
  f32x4 r = {};
#pragma unroll
  for (int z = 0; z < 8; ++z) r += *(const f32x4*)&p[(size_t)z * VH + e];
  out[e + 0] = r[0]; out[e + 1] = r[1]; out[e + 2] = r[2]; out[e + 3] = r[3];
}

// merged tail: blocks <2048 = reduce8s (w_grad = model partials - data grad),
// blocks >=2048 (8) = finalize (bias grads + recon scalar).
__global__ void tail_k(const float* __restrict__ pa, const float* __restrict__ pb,
                       const float* __restrict__ sums, float* __restrict__ out) {
  const int b = blockIdx.x;
  float* outw = out + OUT_WGRAD;
  if (b < 2048) {
    size_t e = ((size_t)b * 256 + threadIdx.x) * 4;
    f32x4 r = {};
#pragma unroll
    for (int z = 0; z < 4; ++z) r += *(const f32x4*)&pa[(size_t)z * VH + e];
#pragma unroll
    for (int z = 0; z < 4; ++z) r += *(const f32x4*)&pb[(size_t)z * VH + e];
    float s0 = outw[e + 0], s1 = outw[e + 1], s2 = outw[e + 2], s3 = outw[e + 3];
    outw[e + 0] = r[0] - s0; outw[e + 1] = r[1] - s1;
    outw[e + 2] = r[2] - s2; outw[e + 3] = r[3] - s3;
  } else {
    const int i = (b - 2048) * 256 + threadIdx.x;   // 0..2047
    const float* recon_p = sums;                 // 256
    const float* vbd = sums + 1024;              // 128 x 2048
    const float* hbd = vbd + 128 * 2048;         // 128 x 1024
    const float* vbm = hbd + 128 * 1024;         // 64 x 2048
    const float* hbm = vbm + 128 * 2048;         // 128 x 1024
    if (i < 2048) {
      float d = 0.f, m = 0.f;
      for (int k = 0; k < 128; ++k) d += vbd[k * 2048 + i];
      for (int k = 0; k < 64; ++k)  m += vbm[k * 2048 + i];
      out[OUT_VBG + i] = m - d;
    }
    if (i < 1024) {
      float d = 0.f, m = 0.f;
      for (int k = 0; k < 128; ++k) { d += hbd[k * 1024 + i]; m += hbm[k * 1024 + i]; }
      out[OUT_HBG + i] = m - d;
    }
    if (i == 0) {
      float s = 0.f;
      for (int k = 0; k < 256; ++k) s += recon_p[k];
      out[OUT_RECON] = s * (1.0f / 16777216.0f);  // /(B*V)
    }
  }
}

extern "C" void kernel_launch(void* const* d_in, const int* in_sizes, int n_in,
                              void* d_out, int out_size, void* d_ws, size_t ws_size,
                              hipStream_t stream) {
  (void)in_sizes; (void)n_in; (void)out_size;
  const float* v   = (const float*)d_in[0];
  const float* w   = (const float*)d_in[1];
  const float* vb  = (const float*)d_in[2];
  const float* hb  = (const float*)d_in[3];
  const float* u_h = (const float*)d_in[4];
  const float* u_v = (const float*)d_in[5];
  float* out = (float*)d_out;
  char* ws = (char*)d_ws;
  if (ws_size < 204734464ULL) return;

  float* sums    = (float*)ws;               // 3.25 MiB region
  float* recon_p = sums;                     // 256
  float* vbd_p   = sums + 1024;              // 128*2048
  float* hbd_p   = vbd_p + 128 * 2048;       // 128*1024
  float* vbm_p   = hbd_p + 128 * 1024;       // 64*2048
  float* hbm_p   = vbm_p + 128 * 2048;       // 128*1024
  char* p = ws + 3407872;
  u16* v_cat  = (u16*)p;  p += (size_t)Bn * 2 * Vn * 2;   // 64 MiB [B,2V]
  u16* wT_cat = (u16*)p;  p += (size_t)Hn * 2 * Vn * 2;   // 8 MiB [H,2V]
  u16* w_cat  = (u16*)p;  p += (size_t)Vn * 2 * Hn * 2;   // 8 MiB [V,2H]
  u16* h_p    = (u16*)p;  p += BH * 2;                    // 16 MiB [B,H]
  u16* hbin   = (u16*)p;  p += BH * 2;                    // 16 MiB [B,H]
  u16* vT     = (u16*)p;  p += (size_t)Vn * Bn * 2;       // 32 MiB [V,B]
  u16* hT     = (u16*)p;  p += (size_t)Hn * Bn * 2;       // 16 MiB [H,B]
  float* big  = (float*)p;                                // 32 MiB time-shared
  u16* vk   = v_cat;            // v_cat dead after g23 (G3 partials overwrite)
  u16* vkT  = vT;               // vT dead after g23
  u16* h2T  = hT;               // hT dead after g23
  float* vcat_f = (float*)v_cat;   // 64 MiB: G3's 8 partials
  float* hpbuf  = (float*)h_p;     // h_p+hbin region (32 MiB) as f32 partials
  float* outW   = out + OUT_WGRAD;

  prep_all_k<<<4608, 256, 0, stream>>>(v, v_cat, vT, vbd_p, w, w_cat, wT_cat);
  // G1a: split-K x2 partials (z0 -> out[0..BH) scratch, z1 -> big)
  gemm256<1><<<dim3(32, 4, 2), 512, 0, stream>>>(
      v_cat, 2 * Vn, wT_cat, 2 * Vn, 3072, nullptr, nullptr, nullptr,
      out, nullptr, nullptr, big, nullptr, nullptr);
  // epi: h_pred / h_p / hbin / hT / hbd
  epi_h_k<1><<<dim3(128, 16), 256, 0, stream>>>(
      out, big, hb, u_h, out, h_p, hbin, hT, hbd_p);
  // merged G2 (recon) + G3 (w_data_grad partials): 512 blocks, one launch
  g23_k<<<512, 512, 0, stream>>>(
      h_p, w_cat, v_cat, vb, recon_p,
      vT, hT, vcat_f, vcat_f + 4 * VH);
  reduce8_k<<<2048, 256, 0, stream>>>(vcat_f, outW);   // outW = data-grad sum
  // G4: vk/vkT + vbm partials (fused sample+transpose epilogue)
  gemm256<4><<<dim3(32, 8), 512, 0, stream>>>(
      hbin, Hn, w_cat, 2 * Hn, 2 * Hn, vb, u_v, nullptr,
      nullptr, vk, nullptr, nullptr, vkT, vbm_p);
  // G5a: split-K x2 partials (z0 -> hpbuf, z1 -> big); h_p/hbin dead now
  gemm256<5><<<dim3(32, 4, 2), 512, 0, stream>>>(
      vk, Vn, wT_cat, 2 * Vn, 2048, nullptr, nullptr, nullptr,
      hpbuf, nullptr, nullptr, big, nullptr, nullptr);
  // epi: h2T + hbm
  epi_h_k<5><<<dim3(128, 16), 256, 0, stream>>>(
      hpbuf, big, hb, u_h + BH, nullptr, nullptr, nullptr, h2T, hbm_p);
  // G6: w_model_grad partials (split-K x8: z<4 -> hpbuf, z>=4 -> big)
  gemm256<3><<<dim3(Vn / 256, Hn / 256, 8), 512, 0, stream>>>(
      vkT, Bn, h2T, Bn, 1024, nullptr, nullptr, nullptr,
      hpbuf, nullptr, nullptr, big, nullptr, nullptr);
  // merged reduce8s + finalize
  tail_k<<<2056, 256, 0, stream>>>(hpbuf, big, sums, out);
}

// Round 11
// 495.255 us; speedup vs baseline: 1.0508x; 1.0508x over previous
//
#include <hip/hip_runtime.h>

// RBM CD-1 step on MI355X — round 19 = REVERT to round-17 (verified 492.3us).
// r18's 16x16x32 -> 32x32x16 shape switch introduced 9.4M LDS bank conflicts
// per GEMM dispatch (exactly 4 cyc per b128 fragment read; was 0) and lost
// 28us. Measured fact: on this [256][32]-u16 slab layout, 32-row-span b128
// reads with 1-bit slot variation conflict ~4cyc/read; the 16-row x 4-slot
// pattern (16x16x32 fragments) is conflict-free. Mechanism underived ->
// revert, no bundled changes.
// Structure: 256x256 tile, BK=32, 8 waves, 2-phase-per-K-tile counted
// pipeline (vmcnt 8/4/0), MODE-3 z-slice XCD swizzle, merged g23/tail.

typedef unsigned short u16;
typedef short s16x8 __attribute__((ext_vector_type(8)));
typedef float f32x4 __attribute__((ext_vector_type(4)));
typedef u16 u16x4 __attribute__((ext_vector_type(4)));
typedef u16 u16x8 __attribute__((ext_vector_type(8)));

constexpr int Bn = 8192, Vn = 2048, Hn = 1024;
constexpr size_t VH = (size_t)Vn * Hn;
constexpr size_t BH = (size_t)Bn * Hn;
constexpr size_t OUT_RECON = BH;                        // 8388608
constexpr size_t OUT_WGRAD = OUT_RECON + 1;             // 8388609
constexpr size_t OUT_VBG   = OUT_WGRAD + VH;            // 10485761
constexpr size_t OUT_HBG   = OUT_VBG + Vn;              // 10487809

__device__ __forceinline__ u16 f2bf(float x) {
  union { float f; unsigned u; } a; a.f = x;
  unsigned r = a.u + 0x7FFFu + ((a.u >> 16) & 1u);   // RNE
  return (u16)(r >> 16);
}
__device__ __forceinline__ float bf2f(u16 h) {
  union { unsigned u; float f; } a; a.u = ((unsigned)h) << 16;
  return a.f;
}
__device__ __forceinline__ float sigmoidf_(float x) {
  return 1.0f / (1.0f + __expf(-x));
}

using gptr_t = const unsigned int __attribute__((address_space(1)))*;
using lptr_t = unsigned int __attribute__((address_space(3)))*;

__device__ __forceinline__ void gload16(const u16* g, u16* l) {
  __builtin_amdgcn_global_load_lds((gptr_t)(unsigned long long)g,
                                   (lptr_t)(unsigned long long)l, 16, 0, 0);
}

// ---------------- merged prep kernel ----------------
// blocks [0,4096): v[B,V] f32 -> v_cat[B,2V]=[hi|lo], vT[V,B], vbd partials.
// blocks [4096,4608): w[V,H] f32 -> w_cat[V,2H], wT_cat[H,2V].
__global__ void prep_all_k(const float* __restrict__ v, u16* __restrict__ vcat,
                           u16* __restrict__ vT, float* __restrict__ vbd_p,
                           const float* __restrict__ w, u16* __restrict__ w_cat,
                           u16* __restrict__ wTc) {
  __shared__ u16 tile16[64][68];
  __shared__ float cs[16][64];
  __shared__ float tile32[64][65];
  const int bx = blockIdx.x;
  const int t = threadIdx.x;
  if (bx < 4096) {
    const int b0 = (bx & 127) << 6, c0 = (bx >> 7) << 6;
    const int rg = t >> 4;          // 0..15 row group
    const int cg = (t & 15) << 2;   // col *4
    float ca[4] = {0.f, 0.f, 0.f, 0.f};
#pragma unroll
    for (int i = 0; i < 4; ++i) {
      int r = rg + 16 * i;
      f32x4 x = *(const f32x4*)&v[(size_t)(b0 + r) * Vn + c0 + cg];
      u16x4 hi, lo;
#pragma unroll
      for (int j = 0; j < 4; ++j) {
        hi[j] = f2bf(x[j]);
        lo[j] = f2bf(x[j] - bf2f(hi[j]));
        tile16[r][cg + j] = hi[j];
        ca[j] += x[j];
      }
      *(u16x4*)&vcat[(size_t)(b0 + r) * (2 * Vn) + c0 + cg] = hi;
      *(u16x4*)&vcat[(size_t)(b0 + r) * (2 * Vn) + Vn + c0 + cg] = lo;
    }
#pragma unroll
    for (int j = 0; j < 4; ++j) cs[rg][cg + j] = ca[j];
    __syncthreads();
    if (t < 64) {
      float s = 0.f;
#pragma unroll
      for (int k = 0; k < 16; ++k) s += cs[k][t];
      vbd_p[(size_t)(bx & 127) * Vn + c0 + t] = s;   // [128][2048]
    }
#pragma unroll
    for (int s2 = 0; s2 < 2; ++s2) {
      int c = t >> 2;
      int seg = (t & 3) + 4 * s2;
      u16x8 pk;
#pragma unroll
      for (int i = 0; i < 8; ++i) pk[i] = tile16[seg * 8 + i][c];
      *(u16x8*)&vT[(size_t)(c0 + c) * Bn + b0 + seg * 8] = pk;
    }
  } else {
    const int wb = bx - 4096;
    const int v0 = (wb & 31) << 6, h0 = (wb >> 5) << 6;
    const int c = t & 63, r = t >> 6;
    for (int rr = r; rr < 64; rr += 4) {
      float x = w[(size_t)(v0 + rr) * Hn + h0 + c];
      tile32[rr][c] = x;
      u16 hi = f2bf(x), lo = f2bf(x - bf2f(hi));
      w_cat[(size_t)(v0 + rr) * (2 * Hn) + h0 + c]      = hi;
      w_cat[(size_t)(v0 + rr) * (2 * Hn) + Hn + h0 + c] = lo;
    }
    __syncthreads();
    for (int rr = r; rr < 64; rr += 4) {
      float x = tile32[c][rr];  // = w[v0+c][h0+rr]
      u16 hi = f2bf(x), lo = f2bf(x - bf2f(hi));
      size_t ro = (size_t)(h0 + rr) * (2 * Vn);
      wTc[ro + v0 + c]      = hi;
      wTc[ro + Vn + v0 + c] = lo;
    }
  }
}

// ---- sampling epilogue for split-K [B,H] pre-activations ----------------
template <int M>
__global__ void epi_h_k(const float* __restrict__ p0, const float* __restrict__ p1,
                        const float* __restrict__ bias, const float* __restrict__ uni,
                        float* __restrict__ f32out, u16* __restrict__ hp_out,
                        u16* __restrict__ hbin_out, u16* __restrict__ tout,
                        float* __restrict__ colp) {
  __shared__ u16 tile[64][68];
  __shared__ float cs[16][64];
  const int b0 = blockIdx.x * 64, c0 = blockIdx.y * 64;
  const int t = threadIdx.x;
  const int rg = t >> 4, cg = (t & 15) << 2;
  float ca[4] = {0.f, 0.f, 0.f, 0.f};
#pragma unroll
  for (int i = 0; i < 4; ++i) {
    int r = rg + 16 * i;
    size_t e = (size_t)(b0 + r) * Hn + c0 + cg;
    f32x4 a = *(const f32x4*)&p0[e];
    f32x4 b = *(const f32x4*)&p1[e];
    f32x4 uu = *(const f32x4*)&uni[e];
    f32x4 hpv;
    u16x4 hb16, qv;
#pragma unroll
    for (int j = 0; j < 4; ++j) {
      float hp = sigmoidf_(a[j] + b[j] + bias[c0 + cg + j]);
      u16 qb = (hp > uu[j]) ? (u16)0x3F80 : (u16)0;
      tile[r][cg + j] = qb;
      if constexpr (M == 1) {
        hpv[j] = hp; hb16[j] = f2bf(hp); qv[j] = qb;
        ca[j] += hp;
      } else {
        ca[j] += (qb ? 1.f : 0.f);
      }
    }
    if constexpr (M == 1) {
      *(f32x4*)&f32out[e] = hpv;        // h_prediction (overwrites p0 region)
      *(u16x4*)&hp_out[e] = hb16;
      *(u16x4*)&hbin_out[e] = qv;
    }
  }
#pragma unroll
  for (int j = 0; j < 4; ++j) cs[rg][cg + j] = ca[j];
  __syncthreads();
  if (t < 64) {
    float s = 0.f;
#pragma unroll
    for (int k = 0; k < 16; ++k) s += cs[k][t];
    colp[(size_t)blockIdx.x * Hn + c0 + t] = s;   // [128][1024]
  }
#pragma unroll
  for (int s2 = 0; s2 < 2; ++s2) {
    int c = t >> 2;
    int seg = (t & 3) + 4 * s2;
    u16x8 pk;
#pragma unroll
    for (int i = 0; i < 8; ++i) pk[i] = tile[seg * 8 + i][c];
    *(u16x8*)&tout[(size_t)(c0 + c) * Bn + b0 + seg * 8] = pk;
  }
}

// ---------------- GEMM 256x256, BK=32, 8 waves, 2-phase counted pipeline --
// MODE 1: G1 split-K x2 partial (A remap [hi|hi|lo], B remap [hi|lo|hi]).
// MODE 3: split-K x8 grad (G6): A,B += z*K cols -> (z<4?f32out:redp)+(z&3)*VH.
// MODE 4: G4 vk: A=hbin (dup), B=w_cat, K=2048 -> vk, vkT, vbm (fused).
// MODE 5: G5 split-K x2 partial: A=vk (dup), B=wT_cat.
template <int MODE>
__global__ __launch_bounds__(512) void gemm256(
    const u16* __restrict__ A, int lda, const u16* __restrict__ Bm, int ldb, int K,
    const float* __restrict__ bias, const float* __restrict__ uni,
    const float* __restrict__ aux, float* __restrict__ f32out,
    u16* __restrict__ bfout, const u16* __restrict__ aux16,
    float* __restrict__ redp, u16* __restrict__ tout, float* __restrict__ colp) {
  constexpr bool TRANS = (MODE == 4);
  // As[4][256][32] at 0 (32768 u16), Bs[4][256][32] at 32768; 128 KB.
  // MODE4 epilogue ebuf [256][264] (67584 u16 = 132 KB) aliases everything.
  __shared__ __align__(16) u16 smem[TRANS ? 67584 : 65536];
  const int t = threadIdx.x;
  const int lane = t & 63, wave = t >> 6;                // 8 waves
  const int wr = (wave >> 2) << 7;                       // 0 / 128
  const int wc = (wave & 3) << 6;                        // 0/64/128/192
  // MODE-3-only XCD swizzle: grid (8,4,8), z = K-slice. HW: XCD = linear%8
  // (confirmed r12). Remap so XCD k owns z-slice k's full 8x4 MxN grid.
  int bidx = blockIdx.x, bidy = blockIdx.y, bidz = blockIdx.z;
  if constexpr (MODE == 3) {
    const int orig = blockIdx.x + (blockIdx.y << 3) + (blockIdx.z << 5);
    bidz = orig & 7;
    const int r = orig >> 3;       // 0..31 rank within XCD
    bidx = r & 7;
    bidy = r >> 3;
  }
  const int bm = bidx << 8, bn = bidy << 8;
  int kbeg = 0;
  float* pout = f32out;
  if constexpr (MODE == 1 || MODE == 5) {
    kbeg = bidz * K;
    pout = (bidz == 0) ? f32out : redp;
  }
  if constexpr (MODE == 3) {
    size_t off = (size_t)bidz * (size_t)K;
    A += off;
    Bm += off;
    pout = ((bidz < 4) ? f32out : redp) + (size_t)(bidz & 3) * VH;
  }
  f32x4 acc[8][4] = {};
  // staging (one gload = 512 thr x 16B = 128 rows x 64B): LDS row sr = t>>2,
  // granule t&3; fetch SWIZZLED global granule (t&3) ^ ((row>>1)&3) [r5 T2].
  const int sr = t >> 2;
  const int sc = (((t & 3) ^ ((t >> 3) & 3)) << 3);
  const u16* Ag  = A  + (size_t)(bm + sr) * lda + sc;
  const u16* Ag2 = Ag + (size_t)128 * lda;
  const u16* Bg  = Bm + (size_t)(bn + sr) * ldb + sc;
  const u16* Bg2 = Bg + (size_t)128 * ldb;
  const int fr = lane & 15, fg = lane >> 4;
  const int ga = ((fg ^ ((fr >> 1) & 3)) << 3);          // swizzled read granule

  auto acolf = [&](int k0) -> int {
    if constexpr (MODE == 1)      return (k0 < 2048) ? k0 : k0 - 2048;  // [hi|hi|lo]
    else if constexpr (MODE == 4) return k0 & 1023;
    else if constexpr (MODE == 5) return k0 & 2047;
    else                          return k0;
  };
  auto bcolf = [&](int k0) -> int {
    if constexpr (MODE == 1) return (k0 < 4096) ? k0 : k0 - 4096;       // [hi|lo|hi]
    else                     return k0;
  };
  auto stageA = [&](int kt) {
    const int k0 = kbeg + (kt << 5);
    const int acol = acolf(k0);
    u16* ad = smem + (kt & 3) * 8192 + wave * 512;       // wave-uniform base
    gload16(Ag + acol, ad);
    gload16(Ag2 + acol, ad + 4096);
  };
  auto stageB = [&](int kt) {
    const int k0 = kbeg + (kt << 5);
    const int bcol = bcolf(k0);
    u16* bd = smem + 32768 + (kt & 3) * 8192 + wave * 512;
    gload16(Bg + bcol, bd);
    gload16(Bg2 + bcol, bd + 4096);
  };
  // MODE 4 epilogue-tile L2 prefetch: one probe per 128B L2 line;
  // uni f32 [256][256] tile = 2048 lines = 4 chunks x 512 thr.
  auto pfl4 = [&](int ci) -> float {
    const int L = (ci << 9) + t;         // 0..2047
    return uni[(size_t)(bm + (L >> 3)) * Vn + bn + ((L & 7) << 5)];
  };

  // 2-phase-per-tile counted pipeline (depth-4 slabs, pb = kt&3):
  // steady outstanding at phase-B vmcnt = 12 -> vmcnt(8) guards tile kt+1.
  const int NT = K >> 5;               // >= 32 for all modes
  const int pfbeg = NT - 8;            // probes at kt in [NT-8, NT-4)
  stageA(0); stageB(0); stageA(1); stageB(1); stageA(2); stageB(2);
  asm volatile("s_waitcnt vmcnt(8)" ::: "memory");
  __builtin_amdgcn_s_barrier();
  asm volatile("" ::: "memory");
  s16x8 bf[4], af[4];
  for (int kt = 0; kt < NT; ++kt) {
    const int pb = kt & 3;
    const u16* Ab = smem + pb * 8192;
    const u16* Bb = smem + 32768 + pb * 8192;
    const bool st = (kt < NT - 3);
    // ---- phase A: reads + A-stage + barrier + MFMA lo ----
#pragma unroll
    for (int n = 0; n < 4; ++n)
      bf[n] = *(const s16x8*)&Bb[(wc + n * 16 + fr) * 32 + ga];
#pragma unroll
    for (int m = 0; m < 4; ++m)
      af[m] = *(const s16x8*)&Ab[(wr + m * 16 + fr) * 32 + ga];
    if (st) stageA(kt + 3);
    if constexpr (MODE == 4) {
      if (kt >= pfbeg && kt < pfbeg + 4) {
        float pfv = pfl4(kt - pfbeg);
        asm volatile("" :: "v"(pfv));
      }
    }
    __builtin_amdgcn_s_barrier();
    asm volatile("" ::: "memory");
    __builtin_amdgcn_s_setprio(1);
#pragma unroll
    for (int m = 0; m < 4; ++m)
#pragma unroll
      for (int n = 0; n < 4; ++n)
        acc[m][n] = __builtin_amdgcn_mfma_f32_16x16x32_bf16(af[m], bf[n], acc[m][n], 0, 0, 0);
    __builtin_amdgcn_s_setprio(0);
    // ---- phase B: reads + B-stage + vmcnt + barrier + MFMA hi ----
#pragma unroll
    for (int m = 0; m < 4; ++m)
      af[m] = *(const s16x8*)&Ab[(wr + (m + 4) * 16 + fr) * 32 + ga];
    if (st) stageB(kt + 3);
    if (kt < NT - 3) {
      asm volatile("s_waitcnt vmcnt(8)" ::: "memory");
    } else if (kt == NT - 3) {
      asm volatile("s_waitcnt vmcnt(4)" ::: "memory");
    } else if (kt == NT - 2) {
      asm volatile("s_waitcnt vmcnt(0)" ::: "memory");
    }
    __builtin_amdgcn_s_barrier();
    asm volatile("" ::: "memory");
    __builtin_amdgcn_s_setprio(1);
#pragma unroll
    for (int m = 0; m < 4; ++m)
#pragma unroll
      for (int n = 0; n < 4; ++n)
        acc[m + 4][n] = __builtin_amdgcn_mfma_f32_16x16x32_bf16(af[m], bf[n], acc[m + 4][n], 0, 0, 0);
    __builtin_amdgcn_s_setprio(0);
  }

  // ---- epilogue ----
  constexpr int NC = (MODE == 4) ? Vn : Hn;
  const int fq = lane >> 4;

  if constexpr (MODE == 1 || MODE == 3 || MODE == 5) {
#pragma unroll
    for (int m = 0; m < 8; ++m)
#pragma unroll
      for (int n = 0; n < 4; ++n)
#pragma unroll
        for (int j = 0; j < 4; ++j) {
          int rl = wr + m * 16 + fq * 4 + j;
          int cl = wc + n * 16 + fr;
          pout[(size_t)(bm + rl) * NC + bn + cl] = acc[m][n][j];
        }
  }

  if constexpr (MODE == 4) {
    __syncthreads();   // all waves done with dbuf before ebuf writes
    float bcol[4];
#pragma unroll
    for (int n = 0; n < 4; ++n) bcol[n] = bias[bn + wc + n * 16 + fr];
    const size_t ebase = (size_t)(bm + wr + fq * 4) * NC + (bn + wc + fr);
    float ux[8][4];
    auto ld4 = [&](int ci, float* dst) {
      size_t e0 = ebase + (size_t)((ci >> 2) << 4) * NC + ((ci & 3) << 4);
      dst[0] = uni[e0];          dst[1] = uni[e0 + NC];
      dst[2] = uni[e0 + 2 * NC]; dst[3] = uni[e0 + 3 * NC];
    };
#pragma unroll
    for (int ci = 0; ci < 8; ++ci) ld4(ci, ux[ci]);
#pragma unroll
    for (int m = 0; m < 8; ++m)
#pragma unroll
      for (int n = 0; n < 4; ++n)
#pragma unroll
        for (int j = 0; j < 4; ++j)
          acc[m][n][j] = sigmoidf_(acc[m][n][j] + bcol[n]);
    float csum[4] = {0.f, 0.f, 0.f, 0.f};
#pragma unroll
    for (int ci = 0; ci < 32; ++ci) {
      const int m = ci >> 2, n = ci & 3;
      const int rl = wr + m * 16 + fq * 4;
      const int cl = wc + n * 16 + fr;
#pragma unroll
      for (int j = 0; j < 4; ++j) {
        u16 qb = (acc[m][n][j] > ux[ci & 7][j]) ? (u16)0x3F80 : (u16)0;
        smem[(rl + j) * 264 + cl] = qb;          // ebuf (feeds vk AND vkT)
        csum[n] += (qb ? 1.f : 0.f);
      }
      if (ci < 24) ld4(ci + 8, ux[ci & 7]);
    }
    // vbm partials: lane covers 32 rows; xor16+xor32 reduces fq -> 128 rows
#pragma unroll
    for (int n = 0; n < 4; ++n) {
      float s = csum[n];
      s += __shfl_xor(s, 16);
      s += __shfl_xor(s, 32);
      if (fq == 0)
        colp[(size_t)(blockIdx.x * 2 + (wr >> 7)) * NC + (bn + wc + n * 16 + fr)] = s;
    }
    __syncthreads();   // ebuf fully written
    // vk row-major writeout: coalesced u16x8 from ebuf. 256 rows x 32
    // col-chunks = 8192 tasks / 512 thr; consecutive threads fill one row.
#pragma unroll
    for (int it = 0; it < 16; ++it) {
      int id = t + (it << 9);
      int r = id >> 5;                   // 0..255
      int c0 = (id & 31) << 3;           // 0..248
      u16x8 pk = *(const u16x8*)&smem[r * 264 + c0];
      *(u16x8*)&bfout[(size_t)(bm + r) * NC + bn + c0] = pk;
    }
    // transposed write-out, 64B-contiguous per thread: thread owns
    // (col c, 32-row span q*32); 4x u16x8 stores land in ONE 64B line.
#pragma unroll
    for (int it = 0; it < 4; ++it) {
      int id = t + (it << 9);
      int c = id & 255;
      int q = id >> 8;                   // 0..7
#pragma unroll
      for (int i8 = 0; i8 < 4; ++i8) {
        u16x8 pk;
#pragma unroll
        for (int i2 = 0; i2 < 8; ++i2)
          pk[i2] = smem[(q * 32 + i8 * 8 + i2) * 264 + c];
        *(u16x8*)&tout[(size_t)(bn + c) * Bn + bm + q * 32 + i8 * 8] = pk;
      }
    }
  }
}

// ---------------- merged G2+G3 (512 blocks, one launch) -------------------
// flat < 256:  G2 recon. A=h_p[B,H], B=w_cat hi, K=1024, NC=2048;
//              epilogue: sigmoid + |v_hi - vp| partial -> redp2[bidy*32+bidx].
// flat >= 256: G3 grad. A=vT+z*1024, B=hT+z*1024 (ld=Bn), K=1024, NC=1024;
//              z-slice XCD swizzle (flat%8 preserved: 256 == 0 mod 8).
__global__ __launch_bounds__(512) void g23_k(
    const u16* __restrict__ A2, const u16* __restrict__ B2,
    const u16* __restrict__ aux16, const float* __restrict__ bias2,
    float* __restrict__ redp2,
    const u16* __restrict__ A3, const u16* __restrict__ B3,
    float* __restrict__ out30, float* __restrict__ out34) {
  __shared__ __align__(16) u16 smem[65536];
  const int t = threadIdx.x;
  const int lane = t & 63, wave = t >> 6;
  const int wr = (wave >> 2) << 7;
  const int wc = (wave & 3) << 6;
  const int flat = blockIdx.x;
  const bool isG2 = (flat < 256);
  int bidx, bidy, bidz = 0;
  const u16 *Abase, *Bbase;
  int lda, ldb;
  if (isG2) {
    bidx = flat & 31; bidy = flat >> 5;
    Abase = A2; Bbase = B2; lda = Hn; ldb = 2 * Hn;
  } else {
    const int orig = flat - 256;
    bidz = orig & 7;
    const int rr = orig >> 3;          // 0..31 rank within XCD
    bidx = rr & 7; bidy = rr >> 3;
    Abase = A3 + (size_t)bidz * 1024;
    Bbase = B3 + (size_t)bidz * 1024;
    lda = Bn; ldb = Bn;
  }
  const int bm = bidx << 8, bn = bidy << 8;
  f32x4 acc[8][4] = {};
  const int sr = t >> 2;
  const int sc = (((t & 3) ^ ((t >> 3) & 3)) << 3);
  const u16* Ag  = Abase + (size_t)(bm + sr) * lda + sc;
  const u16* Ag2 = Ag + (size_t)128 * lda;
  const u16* Bg  = Bbase + (size_t)(bn + sr) * ldb + sc;
  const u16* Bg2 = Bg + (size_t)128 * ldb;
  const int fr = lane & 15, fg = lane >> 4;
  const int ga = ((fg ^ ((fr >> 1) & 3)) << 3);

  auto stageA = [&](int kt) {
    u16* ad = smem + (kt & 3) * 8192 + wave * 512;
    gload16(Ag + (kt << 5), ad);
    gload16(Ag2 + (kt << 5), ad + 4096);
  };
  auto stageB = [&](int kt) {
    u16* bd = smem + 32768 + (kt & 3) * 8192 + wave * 512;
    gload16(Bg + (kt << 5), bd);
    gload16(Bg2 + (kt << 5), bd + 4096);
  };
  auto pfl2 = [&](int ci) -> unsigned {
    const int L = (ci << 9) + t;         // 0..1023
    return (unsigned)aux16[(size_t)(bm + (L >> 2)) * 4096 + bn + ((L & 3) << 6)];
  };

  constexpr int NT = 32;
  stageA(0); stageB(0); stageA(1); stageB(1); stageA(2); stageB(2);
  asm volatile("s_waitcnt vmcnt(8)" ::: "memory");
  __builtin_amdgcn_s_barrier();
  asm volatile("" ::: "memory");
  s16x8 bf[4], af[4];
  for (int kt = 0; kt < NT; ++kt) {
    const int pb = kt & 3;
    const u16* Ab = smem + pb * 8192;
    const u16* Bb = smem + 32768 + pb * 8192;
    const bool st = (kt < NT - 3);
    // phase A
#pragma unroll
    for (int n = 0; n < 4; ++n)
      bf[n] = *(const s16x8*)&Bb[(wc + n * 16 + fr) * 32 + ga];
#pragma unroll
    for (int m = 0; m < 4; ++m)
      af[m] = *(const s16x8*)&Ab[(wr + m * 16 + fr) * 32 + ga];
    if (st) stageA(kt + 3);
    if (isG2 && kt >= NT - 8 && kt < NT - 6) {
      unsigned pfv = pfl2(kt - (NT - 8));
      asm volatile("" :: "v"(pfv));
    }
    __builtin_amdgcn_s_barrier();
    asm volatile("" ::: "memory");
    __builtin_amdgcn_s_setprio(1);
#pragma unroll
    for (int m = 0; m < 4; ++m)
#pragma unroll
      for (int n = 0; n < 4; ++n)
        acc[m][n] = __builtin_amdgcn_mfma_f32_16x16x32_bf16(af[m], bf[n], acc[m][n], 0, 0, 0);
    __builtin_amdgcn_s_setprio(0);
    // phase B
#pragma unroll
    for (int m = 0; m < 4; ++m)
      af[m] = *(const s16x8*)&Ab[(wr + (m + 4) * 16 + fr) * 32 + ga];
    if (st) stageB(kt + 3);
    if (kt < NT - 3) {
      asm volatile("s_waitcnt vmcnt(8)" ::: "memory");
    } else if (kt == NT - 3) {
      asm volatile("s_waitcnt vmcnt(4)" ::: "memory");
    } else if (kt == NT - 2) {
      asm volatile("s_waitcnt vmcnt(0)" ::: "memory");
    }
    __builtin_amdgcn_s_barrier();
    asm volatile("" ::: "memory");
    __builtin_amdgcn_s_setprio(1);
#pragma unroll
    for (int m = 0; m < 4; ++m)
#pragma unroll
      for (int n = 0; n < 4; ++n)
        acc[m + 4][n] = __builtin_amdgcn_mfma_f32_16x16x32_bf16(af[m], bf[n], acc[m + 4][n], 0, 0, 0);
    __builtin_amdgcn_s_setprio(0);
  }

  const int fq = lane >> 4;
  if (isG2) {
    // pipelined recon vs v_cat-hi (u16, stride 4096), depth-8 window (&7).
    float bcol[4];
#pragma unroll
    for (int n = 0; n < 4; ++n) bcol[n] = bias2[bn + wc + n * 16 + fr];
    const size_t ebase = (size_t)(bm + wr + fq * 4) * 4096 + (bn + wc + fr);
    float ax[8][4];
    auto ld4 = [&](int ci, float* dst) {
      size_t e0 = ebase + (size_t)((ci >> 2) << 4) * 4096 + ((ci & 3) << 4);
      dst[0] = bf2f(aux16[e0]);            dst[1] = bf2f(aux16[e0 + 4096]);
      dst[2] = bf2f(aux16[e0 + 2 * 4096]); dst[3] = bf2f(aux16[e0 + 3 * 4096]);
    };
#pragma unroll
    for (int ci = 0; ci < 8; ++ci) ld4(ci, ax[ci]);
#pragma unroll
    for (int m = 0; m < 8; ++m)
#pragma unroll
      for (int n = 0; n < 4; ++n)
#pragma unroll
        for (int j = 0; j < 4; ++j)
          acc[m][n][j] = sigmoidf_(acc[m][n][j] + bcol[n]);
    float lsum = 0.f;
#pragma unroll
    for (int ci = 0; ci < 32; ++ci) {
      const int m = ci >> 2, n = ci & 3;
#pragma unroll
      for (int j = 0; j < 4; ++j) lsum += fabsf(ax[ci & 7][j] - acc[m][n][j]);
      if (ci < 24) ld4(ci + 8, ax[ci & 7]);
    }
#pragma unroll
    for (int off = 32; off > 0; off >>= 1) lsum += __shfl_down(lsum, off);
    __syncthreads();
    float* redlds = (float*)smem;
    if (lane == 0) redlds[wave] = lsum;
    __syncthreads();
    if (t == 0) {
      float s = 0.f;
#pragma unroll
      for (int wv = 0; wv < 8; ++wv) s += redlds[wv];
      redp2[(size_t)bidy * 32 + bidx] = s;
    }
  } else {
    float* pout = ((bidz < 4) ? out30 : out34) + (size_t)(bidz & 3) * VH;
#pragma unroll
    for (int m = 0; m < 8; ++m)
#pragma unroll
      for (int n = 0; n < 4; ++n)
#pragma unroll
        for (int j = 0; j < 4; ++j) {
          int rl = wr + m * 16 + fq * 4 + j;
          int cl = wc + n * 16 + fr;
          pout[(size_t)(bm + rl) * Hn + bn + cl] = acc[m][n][j];
        }
  }
}

// out[i] = sum_{z<8} p[z][i]  (scalar stores: out base misaligned)
__global__ void reduce8_k(const float* __restrict__ p, float* __restrict__ out) {
  size_t e = ((size_t)blockIdx.x * 256 + threadIdx.x) * 4;
  f32x4 r = {};
#pragma unroll
  for (int z = 0; z < 8; ++z) r += *(const f32x4*)&p[(size_t)z * VH + e];
  out[e + 0] = r[0]; out[e + 1] = r[1]; out[e + 2] = r[2]; out[e + 3] = r[3];
}

// merged tail: blocks <2048 = reduce8s (w_grad = model partials - data grad),
// blocks >=2048 (8) = finalize (bias grads + recon scalar).
__global__ void tail_k(const float* __restrict__ pa, const float* __restrict__ pb,
                       const float* __restrict__ sums, float* __restrict__ out) {
  const int b = blockIdx.x;
  float* outw = out + OUT_WGRAD;
  if (b < 2048) {
    size_t e = ((size_t)b * 256 + threadIdx.x) * 4;
    f32x4 r = {};
#pragma unroll
    for (int z = 0; z < 4; ++z) r += *(const f32x4*)&pa[(size_t)z * VH + e];
#pragma unroll
    for (int z = 0; z < 4; ++z) r += *(const f32x4*)&pb[(size_t)z * VH + e];
    float s0 = outw[e + 0], s1 = outw[e + 1], s2 = outw[e + 2], s3 = outw[e + 3];
    outw[e + 0] = r[0] - s0; outw[e + 1] = r[1] - s1;
    outw[e + 2] = r[2] - s2; outw[e + 3] = r[3] - s3;
  } else {
    const int i = (b - 2048) * 256 + threadIdx.x;   // 0..2047
    const float* recon_p = sums;                 // 256
    const float* vbd = sums + 1024;              // 128 x 2048
    const float* hbd = vbd + 128 * 2048;         // 128 x 1024
    const float* vbm = hbd + 128 * 1024;         // 64 x 2048
    const float* hbm = vbm + 128 * 2048;         // 128 x 1024
    if (i < 2048) {
      float d = 0.f, m = 0.f;
      for (int k = 0; k < 128; ++k) d += vbd[k * 2048 + i];
      for (int k = 0; k < 64; ++k)  m += vbm[k * 2048 + i];
      out[OUT_VBG + i] = m - d;
    }
    if (i < 1024) {
      float d = 0.f, m = 0.f;
      for (int k = 0; k < 128; ++k) { d += hbd[k * 1024 + i]; m += hbm[k * 1024 + i]; }
      out[OUT_HBG + i] = m - d;
    }
    if (i == 0) {
      float s = 0.f;
      for (int k = 0; k < 256; ++k) s += recon_p[k];
      out[OUT_RECON] = s * (1.0f / 16777216.0f);  // /(B*V)
    }
  }
}

extern "C" void kernel_launch(void* const* d_in, const int* in_sizes, int n_in,
                              void* d_out, int out_size, void* d_ws, size_t ws_size,
                              hipStream_t stream) {
  (void)in_sizes; (void)n_in; (void)out_size;
  const float* v   = (const float*)d_in[0];
  const float* w   = (const float*)d_in[1];
  const float* vb  = (const float*)d_in[2];
  const float* hb  = (const float*)d_in[3];
  const float* u_h = (const float*)d_in[4];
  const float* u_v = (const float*)d_in[5];
  float* out = (float*)d_out;
  char* ws = (char*)d_ws;
  if (ws_size < 204734464ULL) return;

  float* sums    = (float*)ws;               // 3.25 MiB region
  float* recon_p = sums;                     // 256
  float* vbd_p   = sums + 1024;              // 128*2048
  float* hbd_p   = vbd_p + 128 * 2048;       // 128*1024
  float* vbm_p   = hbd_p + 128 * 1024;       // 64*2048
  float* hbm_p   = vbm_p + 128 * 2048;       // 128*1024
  char* p = ws + 3407872;
  u16* v_cat  = (u16*)p;  p += (size_t)Bn * 2 * Vn * 2;   // 64 MiB [B,2V]
  u16* wT_cat = (u16*)p;  p += (size_t)Hn * 2 * Vn * 2;   // 8 MiB [H,2V]
  u16* w_cat  = (u16*)p;  p += (size_t)Vn * 2 * Hn * 2;   // 8 MiB [V,2H]
  u16* h_p    = (u16*)p;  p += BH * 2;                    // 16 MiB [B,H]
  u16* hbin   = (u16*)p;  p += BH * 2;                    // 16 MiB [B,H]
  u16* vT     = (u16*)p;  p += (size_t)Vn * Bn * 2;       // 32 MiB [V,B]
  u16* hT     = (u16*)p;  p += (size_t)Hn * Bn * 2;       // 16 MiB [H,B]
  float* big  = (float*)p;                                // 32 MiB time-shared
  u16* vk   = v_cat;            // v_cat dead after g23 (G3 partials overwrite)
  u16* vkT  = vT;               // vT dead after g23
  u16* h2T  = hT;               // hT dead after g23
  float* vcat_f = (float*)v_cat;   // 64 MiB: G3's 8 partials
  float* hpbuf  = (float*)h_p;     // h_p+hbin region (32 MiB) as f32 partials
  float* outW   = out + OUT_WGRAD;

  prep_all_k<<<4608, 256, 0, stream>>>(v, v_cat, vT, vbd_p, w, w_cat, wT_cat);
  // G1a: split-K x2 partials (z0 -> out[0..BH) scratch, z1 -> big)
  gemm256<1><<<dim3(32, 4, 2), 512, 0, stream>>>(
      v_cat, 2 * Vn, wT_cat, 2 * Vn, 3072, nullptr, nullptr, nullptr,
      out, nullptr, nullptr, big, nullptr, nullptr);
  // epi: h_pred / h_p / hbin / hT / hbd
  epi_h_k<1><<<dim3(128, 16), 256, 0, stream>>>(
      out, big, hb, u_h, out, h_p, hbin, hT, hbd_p);
  // merged G2 (recon) + G3 (w_data_grad partials): 512 blocks, one launch
  g23_k<<<512, 512, 0, stream>>>(
      h_p, w_cat, v_cat, vb, recon_p,
      vT, hT, vcat_f, vcat_f + 4 * VH);
  reduce8_k<<<2048, 256, 0, stream>>>(vcat_f, outW);   // outW = data-grad sum
  // G4: vk/vkT + vbm partials (fused sample+transpose epilogue)
  gemm256<4><<<dim3(32, 8), 512, 0, stream>>>(
      hbin, Hn, w_cat, 2 * Hn, 2 * Hn, vb, u_v, nullptr,
      nullptr, vk, nullptr, nullptr, vkT, vbm_p);
  // G5a: split-K x2 partials (z0 -> hpbuf, z1 -> big); h_p/hbin dead now
  gemm256<5><<<dim3(32, 4, 2), 512, 0, stream>>>(
      vk, Vn, wT_cat, 2 * Vn, 2048, nullptr, nullptr, nullptr,
      hpbuf, nullptr, nullptr, big, nullptr, nullptr);
  // epi: h2T + hbm
  epi_h_k<5><<<dim3(128, 16), 256, 0, stream>>>(
      hpbuf, big, hb, u_h + BH, nullptr, nullptr, nullptr, h2T, hbm_p);
  // G6: w_model_grad partials (split-K x8: z<4 -> hpbuf, z>=4 -> big)
  gemm256<3><<<dim3(Vn / 256, Hn / 256, 8), 512, 0, stream>>>(
      vkT, Bn, h2T, Bn, 1024, nullptr, nullptr, nullptr,
      hpbuf, nullptr, nullptr, big, nullptr, nullptr);
  // merged reduce8s + finalize
  tail_k<<<2056, 256, 0, stream>>>(hpbuf, big, sums, out);
}

// Round 12
// 479.661 us; speedup vs baseline: 1.0849x; 1.0325x over previous
//
#include <hip/hip_runtime.h>

// RBM CD-1 step on MI355X — round 20.
// = round-19 kernel (r17-equivalent, verified ~492-495us) + EXACT i8 path
// for G6 (w_model_grad): vkT and h2T are binary {0,1} -> store as u8 and
// compute G6 with mfma_i32_16x16x64_i8 (2x bf16 rate, m16). The i8 slab
// [256 rows][64B] is byte-identical to the bf16 [256][32] slab: same
// staging, same granule swizzle, same 16-row x 4-slot fragment pattern
// (measured conflict-free). i32 accum (<= 8192, exact) -> f32 store.
//  - gemm_i8_k: MODE-3 clone (2-phase depth-4 vmcnt 8/4/0, z-slice XCD
//    swizzle), NT=16 tiles of K=64 i8.
//  - G4 vkT writeout -> u8, 128B-contiguous per thread (full-line writes).
//  - epi_h<5> h2T -> u8.
// All other kernels byte-identical to r19. Numerics exact: absmax unchanged.

typedef unsigned short u16;
typedef unsigned char u8;
typedef short s16x8 __attribute__((ext_vector_type(8)));
typedef float f32x4 __attribute__((ext_vector_type(4)));
typedef int i32x4 __attribute__((ext_vector_type(4)));
typedef u16 u16x4 __attribute__((ext_vector_type(4)));
typedef u16 u16x8 __attribute__((ext_vector_type(8)));
typedef u8 u8x8 __attribute__((ext_vector_type(8)));

constexpr int Bn = 8192, Vn = 2048, Hn = 1024;
constexpr size_t VH = (size_t)Vn * Hn;
constexpr size_t BH = (size_t)Bn * Hn;
constexpr size_t OUT_RECON = BH;                        // 8388608
constexpr size_t OUT_WGRAD = OUT_RECON + 1;             // 8388609
constexpr size_t OUT_VBG   = OUT_WGRAD + VH;            // 10485761
constexpr size_t OUT_HBG   = OUT_VBG + Vn;              // 10487809

__device__ __forceinline__ u16 f2bf(float x) {
  union { float f; unsigned u; } a; a.f = x;
  unsigned r = a.u + 0x7FFFu + ((a.u >> 16) & 1u);   // RNE
  return (u16)(r >> 16);
}
__device__ __forceinline__ float bf2f(u16 h) {
  union { unsigned u; float f; } a; a.u = ((unsigned)h) << 16;
  return a.f;
}
__device__ __forceinline__ float sigmoidf_(float x) {
  return 1.0f / (1.0f + __expf(-x));
}

using gptr_t = const unsigned int __attribute__((address_space(1)))*;
using lptr_t = unsigned int __attribute__((address_space(3)))*;

__device__ __forceinline__ void gload16(const void* g, void* l) {
  __builtin_amdgcn_global_load_lds((gptr_t)(unsigned long long)g,
                                   (lptr_t)(unsigned long long)l, 16, 0, 0);
}

// ---------------- merged prep kernel ----------------
// blocks [0,4096): v[B,V] f32 -> v_cat[B,2V]=[hi|lo], vT[V,B], vbd partials.
// blocks [4096,4608): w[V,H] f32 -> w_cat[V,2H], wT_cat[H,2V].
__global__ void prep_all_k(const float* __restrict__ v, u16* __restrict__ vcat,
                           u16* __restrict__ vT, float* __restrict__ vbd_p,
                           const float* __restrict__ w, u16* __restrict__ w_cat,
                           u16* __restrict__ wTc) {
  __shared__ u16 tile16[64][68];
  __shared__ float cs[16][64];
  __shared__ float tile32[64][65];
  const int bx = blockIdx.x;
  const int t = threadIdx.x;
  if (bx < 4096) {
    const int b0 = (bx & 127) << 6, c0 = (bx >> 7) << 6;
    const int rg = t >> 4;          // 0..15 row group
    const int cg = (t & 15) << 2;   // col *4
    float ca[4] = {0.f, 0.f, 0.f, 0.f};
#pragma unroll
    for (int i = 0; i < 4; ++i) {
      int r = rg + 16 * i;
      f32x4 x = *(const f32x4*)&v[(size_t)(b0 + r) * Vn + c0 + cg];
      u16x4 hi, lo;
#pragma unroll
      for (int j = 0; j < 4; ++j) {
        hi[j] = f2bf(x[j]);
        lo[j] = f2bf(x[j] - bf2f(hi[j]));
        tile16[r][cg + j] = hi[j];
        ca[j] += x[j];
      }
      *(u16x4*)&vcat[(size_t)(b0 + r) * (2 * Vn) + c0 + cg] = hi;
      *(u16x4*)&vcat[(size_t)(b0 + r) * (2 * Vn) + Vn + c0 + cg] = lo;
    }
#pragma unroll
    for (int j = 0; j < 4; ++j) cs[rg][cg + j] = ca[j];
    __syncthreads();
    if (t < 64) {
      float s = 0.f;
#pragma unroll
      for (int k = 0; k < 16; ++k) s += cs[k][t];
      vbd_p[(size_t)(bx & 127) * Vn + c0 + t] = s;   // [128][2048]
    }
#pragma unroll
    for (int s2 = 0; s2 < 2; ++s2) {
      int c = t >> 2;
      int seg = (t & 3) + 4 * s2;
      u16x8 pk;
#pragma unroll
      for (int i = 0; i < 8; ++i) pk[i] = tile16[seg * 8 + i][c];
      *(u16x8*)&vT[(size_t)(c0 + c) * Bn + b0 + seg * 8] = pk;
    }
  } else {
    const int wb = bx - 4096;
    const int v0 = (wb & 31) << 6, h0 = (wb >> 5) << 6;
    const int c = t & 63, r = t >> 6;
    for (int rr = r; rr < 64; rr += 4) {
      float x = w[(size_t)(v0 + rr) * Hn + h0 + c];
      tile32[rr][c] = x;
      u16 hi = f2bf(x), lo = f2bf(x - bf2f(hi));
      w_cat[(size_t)(v0 + rr) * (2 * Hn) + h0 + c]      = hi;
      w_cat[(size_t)(v0 + rr) * (2 * Hn) + Hn + h0 + c] = lo;
    }
    __syncthreads();
    for (int rr = r; rr < 64; rr += 4) {
      float x = tile32[c][rr];  // = w[v0+c][h0+rr]
      u16 hi = f2bf(x), lo = f2bf(x - bf2f(hi));
      size_t ro = (size_t)(h0 + rr) * (2 * Vn);
      wTc[ro + v0 + c]      = hi;
      wTc[ro + Vn + v0 + c] = lo;
    }
  }
}

// ---- sampling epilogue for split-K [B,H] pre-activations ----------------
// M==1: writes h_pred f32 / h_p bf16 / hbin bf16 / hT bf16 (u16), hbd colsums.
// M==5: writes h2T as u8 {0,1} (feeds i8 G6), hbm colsums.
template <int M>
__global__ void epi_h_k(const float* __restrict__ p0, const float* __restrict__ p1,
                        const float* __restrict__ bias, const float* __restrict__ uni,
                        float* __restrict__ f32out, u16* __restrict__ hp_out,
                        u16* __restrict__ hbin_out, u16* __restrict__ tout,
                        float* __restrict__ colp) {
  __shared__ u16 tile[64][68];
  __shared__ float cs[16][64];
  const int b0 = blockIdx.x * 64, c0 = blockIdx.y * 64;
  const int t = threadIdx.x;
  const int rg = t >> 4, cg = (t & 15) << 2;
  float ca[4] = {0.f, 0.f, 0.f, 0.f};
#pragma unroll
  for (int i = 0; i < 4; ++i) {
    int r = rg + 16 * i;
    size_t e = (size_t)(b0 + r) * Hn + c0 + cg;
    f32x4 a = *(const f32x4*)&p0[e];
    f32x4 b = *(const f32x4*)&p1[e];
    f32x4 uu = *(const f32x4*)&uni[e];
    f32x4 hpv;
    u16x4 hb16, qv;
#pragma unroll
    for (int j = 0; j < 4; ++j) {
      float hp = sigmoidf_(a[j] + b[j] + bias[c0 + cg + j]);
      u16 qb = (hp > uu[j]) ? (u16)0x3F80 : (u16)0;
      tile[r][cg + j] = qb;
      if constexpr (M == 1) {
        hpv[j] = hp; hb16[j] = f2bf(hp); qv[j] = qb;
        ca[j] += hp;
      } else {
        ca[j] += (qb ? 1.f : 0.f);
      }
    }
    if constexpr (M == 1) {
      *(f32x4*)&f32out[e] = hpv;        // h_prediction (overwrites p0 region)
      *(u16x4*)&hp_out[e] = hb16;
      *(u16x4*)&hbin_out[e] = qv;
    }
  }
#pragma unroll
  for (int j = 0; j < 4; ++j) cs[rg][cg + j] = ca[j];
  __syncthreads();
  if (t < 64) {
    float s = 0.f;
#pragma unroll
    for (int k = 0; k < 16; ++k) s += cs[k][t];
    colp[(size_t)blockIdx.x * Hn + c0 + t] = s;   // [128][1024]
  }
  if constexpr (M == 5) {
    u8* tout8 = (u8*)tout;
#pragma unroll
    for (int s2 = 0; s2 < 2; ++s2) {
      int c = t >> 2;
      int seg = (t & 3) + 4 * s2;
      u8x8 pk;
#pragma unroll
      for (int i = 0; i < 8; ++i) pk[i] = tile[seg * 8 + i][c] ? (u8)1 : (u8)0;
      *(u8x8*)&tout8[(size_t)(c0 + c) * Bn + b0 + seg * 8] = pk;
    }
  } else {
#pragma unroll
    for (int s2 = 0; s2 < 2; ++s2) {
      int c = t >> 2;
      int seg = (t & 3) + 4 * s2;
      u16x8 pk;
#pragma unroll
      for (int i = 0; i < 8; ++i) pk[i] = tile[seg * 8 + i][c];
      *(u16x8*)&tout[(size_t)(c0 + c) * Bn + b0 + seg * 8] = pk;
    }
  }
}

// ---------------- GEMM 256x256, BK=32, 8 waves, 2-phase counted pipeline --
// MODE 1: G1 split-K x2 partial (A remap [hi|hi|lo], B remap [hi|lo|hi]).
// MODE 3: split-K x8 grad (G3 lives in g23_k now; kept for reference).
// MODE 4: G4 vk: A=hbin (dup), B=w_cat, K=2048 -> vk, vkT(u8), vbm (fused).
// MODE 5: G5 split-K x2 partial: A=vk (dup), B=wT_cat.
template <int MODE>
__global__ __launch_bounds__(512) void gemm256(
    const u16* __restrict__ A, int lda, const u16* __restrict__ Bm, int ldb, int K,
    const float* __restrict__ bias, const float* __restrict__ uni,
    const float* __restrict__ aux, float* __restrict__ f32out,
    u16* __restrict__ bfout, const u16* __restrict__ aux16,
    float* __restrict__ redp, u16* __restrict__ tout, float* __restrict__ colp) {
  constexpr bool TRANS = (MODE == 4);
  // As[4][256][32] at 0 (32768 u16), Bs[4][256][32] at 32768; 128 KB.
  // MODE4 epilogue ebuf [256][264] (67584 u16 = 132 KB) aliases everything.
  __shared__ __align__(16) u16 smem[TRANS ? 67584 : 65536];
  const int t = threadIdx.x;
  const int lane = t & 63, wave = t >> 6;                // 8 waves
  const int wr = (wave >> 2) << 7;                       // 0 / 128
  const int wc = (wave & 3) << 6;                        // 0/64/128/192
  int bidx = blockIdx.x, bidy = blockIdx.y, bidz = blockIdx.z;
  if constexpr (MODE == 3) {
    const int orig = blockIdx.x + (blockIdx.y << 3) + (blockIdx.z << 5);
    bidz = orig & 7;
    const int r = orig >> 3;
    bidx = r & 7;
    bidy = r >> 3;
  }
  const int bm = bidx << 8, bn = bidy << 8;
  int kbeg = 0;
  float* pout = f32out;
  if constexpr (MODE == 1 || MODE == 5) {
    kbeg = bidz * K;
    pout = (bidz == 0) ? f32out : redp;
  }
  if constexpr (MODE == 3) {
    size_t off = (size_t)bidz * (size_t)K;
    A += off;
    Bm += off;
    pout = ((bidz < 4) ? f32out : redp) + (size_t)(bidz & 3) * VH;
  }
  f32x4 acc[8][4] = {};
  // staging (one gload = 512 thr x 16B = 128 rows x 64B): LDS row sr = t>>2,
  // granule t&3; fetch SWIZZLED global granule (t&3) ^ ((row>>1)&3) [r5 T2].
  const int sr = t >> 2;
  const int sc = (((t & 3) ^ ((t >> 3) & 3)) << 3);
  const u16* Ag  = A  + (size_t)(bm + sr) * lda + sc;
  const u16* Ag2 = Ag + (size_t)128 * lda;
  const u16* Bg  = Bm + (size_t)(bn + sr) * ldb + sc;
  const u16* Bg2 = Bg + (size_t)128 * ldb;
  const int fr = lane & 15, fg = lane >> 4;
  const int ga = ((fg ^ ((fr >> 1) & 3)) << 3);          // swizzled read granule

  auto acolf = [&](int k0) -> int {
    if constexpr (MODE == 1)      return (k0 < 2048) ? k0 : k0 - 2048;  // [hi|hi|lo]
    else if constexpr (MODE == 4) return k0 & 1023;
    else if constexpr (MODE == 5) return k0 & 2047;
    else                          return k0;
  };
  auto bcolf = [&](int k0) -> int {
    if constexpr (MODE == 1) return (k0 < 4096) ? k0 : k0 - 4096;       // [hi|lo|hi]
    else                     return k0;
  };
  auto stageA = [&](int kt) {
    const int k0 = kbeg + (kt << 5);
    const int acol = acolf(k0);
    u16* ad = smem + (kt & 3) * 8192 + wave * 512;       // wave-uniform base
    gload16(Ag + acol, ad);
    gload16(Ag2 + acol, ad + 4096);
  };
  auto stageB = [&](int kt) {
    const int k0 = kbeg + (kt << 5);
    const int bcol = bcolf(k0);
    u16* bd = smem + 32768 + (kt & 3) * 8192 + wave * 512;
    gload16(Bg + bcol, bd);
    gload16(Bg2 + bcol, bd + 4096);
  };
  // MODE 4 epilogue-tile L2 prefetch: one probe per 128B L2 line;
  // uni f32 [256][256] tile = 2048 lines = 4 chunks x 512 thr.
  auto pfl4 = [&](int ci) -> float {
    const int L = (ci << 9) + t;         // 0..2047
    return uni[(size_t)(bm + (L >> 3)) * Vn + bn + ((L & 7) << 5)];
  };

  // 2-phase-per-tile counted pipeline (depth-4 slabs, pb = kt&3):
  // steady outstanding at phase-B vmcnt = 12 -> vmcnt(8) guards tile kt+1.
  const int NT = K >> 5;
  const int pfbeg = NT - 8;
  stageA(0); stageB(0); stageA(1); stageB(1); stageA(2); stageB(2);
  asm volatile("s_waitcnt vmcnt(8)" ::: "memory");
  __builtin_amdgcn_s_barrier();
  asm volatile("" ::: "memory");
  s16x8 bf[4], af[4];
  for (int kt = 0; kt < NT; ++kt) {
    const int pb = kt & 3;
    const u16* Ab = smem + pb * 8192;
    const u16* Bb = smem + 32768 + pb * 8192;
    const bool st = (kt < NT - 3);
    // ---- phase A: reads + A-stage + barrier + MFMA lo ----
#pragma unroll
    for (int n = 0; n < 4; ++n)
      bf[n] = *(const s16x8*)&Bb[(wc + n * 16 + fr) * 32 + ga];
#pragma unroll
    for (int m = 0; m < 4; ++m)
      af[m] = *(const s16x8*)&Ab[(wr + m * 16 + fr) * 32 + ga];
    if (st) stageA(kt + 3);
    if constexpr (MODE == 4) {
      if (kt >= pfbeg && kt < pfbeg + 4) {
        float pfv = pfl4(kt - pfbeg);
        asm volatile("" :: "v"(pfv));
      }
    }
    __builtin_amdgcn_s_barrier();
    asm volatile("" ::: "memory");
    __builtin_amdgcn_s_setprio(1);
#pragma unroll
    for (int m = 0; m < 4; ++m)
#pragma unroll
      for (int n = 0; n < 4; ++n)
        acc[m][n] = __builtin_amdgcn_mfma_f32_16x16x32_bf16(af[m], bf[n], acc[m][n], 0, 0, 0);
    __builtin_amdgcn_s_setprio(0);
    // ---- phase B: reads + B-stage + vmcnt + barrier + MFMA hi ----
#pragma unroll
    for (int m = 0; m < 4; ++m)
      af[m] = *(const s16x8*)&Ab[(wr + (m + 4) * 16 + fr) * 32 + ga];
    if (st) stageB(kt + 3);
    if (kt < NT - 3) {
      asm volatile("s_waitcnt vmcnt(8)" ::: "memory");
    } else if (kt == NT - 3) {
      asm volatile("s_waitcnt vmcnt(4)" ::: "memory");
    } else if (kt == NT - 2) {
      asm volatile("s_waitcnt vmcnt(0)" ::: "memory");
    }
    __builtin_amdgcn_s_barrier();
    asm volatile("" ::: "memory");
    __builtin_amdgcn_s_setprio(1);
#pragma unroll
    for (int m = 0; m < 4; ++m)
#pragma unroll
      for (int n = 0; n < 4; ++n)
        acc[m + 4][n] = __builtin_amdgcn_mfma_f32_16x16x32_bf16(af[m], bf[n], acc[m + 4][n], 0, 0, 0);
    __builtin_amdgcn_s_setprio(0);
  }

  // ---- epilogue ----
  constexpr int NC = (MODE == 4) ? Vn : Hn;
  const int fq = lane >> 4;

  if constexpr (MODE == 1 || MODE == 3 || MODE == 5) {
#pragma unroll
    for (int m = 0; m < 8; ++m)
#pragma unroll
      for (int n = 0; n < 4; ++n)
#pragma unroll
        for (int j = 0; j < 4; ++j) {
          int rl = wr + m * 16 + fq * 4 + j;
          int cl = wc + n * 16 + fr;
          pout[(size_t)(bm + rl) * NC + bn + cl] = acc[m][n][j];
        }
  }

  if constexpr (MODE == 4) {
    __syncthreads();   // all waves done with dbuf before ebuf writes
    float bcol[4];
#pragma unroll
    for (int n = 0; n < 4; ++n) bcol[n] = bias[bn + wc + n * 16 + fr];
    const size_t ebase = (size_t)(bm + wr + fq * 4) * NC + (bn + wc + fr);
    float ux[8][4];
    auto ld4 = [&](int ci, float* dst) {
      size_t e0 = ebase + (size_t)((ci >> 2) << 4) * NC + ((ci & 3) << 4);
      dst[0] = uni[e0];          dst[1] = uni[e0 + NC];
      dst[2] = uni[e0 + 2 * NC]; dst[3] = uni[e0 + 3 * NC];
    };
#pragma unroll
    for (int ci = 0; ci < 8; ++ci) ld4(ci, ux[ci]);
#pragma unroll
    for (int m = 0; m < 8; ++m)
#pragma unroll
      for (int n = 0; n < 4; ++n)
#pragma unroll
        for (int j = 0; j < 4; ++j)
          acc[m][n][j] = sigmoidf_(acc[m][n][j] + bcol[n]);
    float csum[4] = {0.f, 0.f, 0.f, 0.f};
#pragma unroll
    for (int ci = 0; ci < 32; ++ci) {
      const int m = ci >> 2, n = ci & 3;
      const int rl = wr + m * 16 + fq * 4;
      const int cl = wc + n * 16 + fr;
#pragma unroll
      for (int j = 0; j < 4; ++j) {
        u16 qb = (acc[m][n][j] > ux[ci & 7][j]) ? (u16)0x3F80 : (u16)0;
        smem[(rl + j) * 264 + cl] = qb;          // ebuf (feeds vk AND vkT)
        csum[n] += (qb ? 1.f : 0.f);
      }
      if (ci < 24) ld4(ci + 8, ux[ci & 7]);
    }
    // vbm partials: lane covers 32 rows; xor16+xor32 reduces fq -> 128 rows
#pragma unroll
    for (int n = 0; n < 4; ++n) {
      float s = csum[n];
      s += __shfl_xor(s, 16);
      s += __shfl_xor(s, 32);
      if (fq == 0)
        colp[(size_t)(blockIdx.x * 2 + (wr >> 7)) * NC + (bn + wc + n * 16 + fr)] = s;
    }
    __syncthreads();   // ebuf fully written
    // vk row-major writeout: coalesced u16x8 from ebuf. 256 rows x 32
    // col-chunks = 8192 tasks / 512 thr; consecutive threads fill one row.
#pragma unroll
    for (int it = 0; it < 16; ++it) {
      int id = t + (it << 9);
      int r = id >> 5;                   // 0..255
      int c0 = (id & 31) << 3;           // 0..248
      u16x8 pk = *(const u16x8*)&smem[r * 264 + c0];
      *(u16x8*)&bfout[(size_t)(bm + r) * NC + bn + c0] = pk;
    }
    // vkT u8 writeout: thread owns (col c, 128-row half) -> 16x u8x8 =
    // 128B contiguous (two full 64B lines per thread).
    {
      u8* tout8 = (u8*)tout;
      const int c = t & 255;
      const int half = t >> 8;           // 0..1
#pragma unroll
      for (int i8_ = 0; i8_ < 16; ++i8_) {
        u8x8 pk;
#pragma unroll
        for (int i2 = 0; i2 < 8; ++i2)
          pk[i2] = smem[(half * 128 + i8_ * 8 + i2) * 264 + c] ? (u8)1 : (u8)0;
        *(u8x8*)&tout8[(size_t)(bn + c) * Bn + bm + half * 128 + i8_ * 8] = pk;
      }
    }
  }
}

// ---------------- i8 GEMM for G6 (binary x binary, exact) -----------------
// A = vkT u8 [V,B], B = h2T u8 [H,B]; split-K x8 over B (z-slice XCD
// swizzle); NT=16 tiles of K=64 i8 (64B rows -> same slab bytes/staging/
// swizzle as the bf16 kernels). mfma_i32_16x16x64_i8; i32 -> f32 partials.
__global__ __launch_bounds__(512) void gemm_i8_k(
    const u8* __restrict__ A, const u8* __restrict__ Bm,
    float* __restrict__ out0, float* __restrict__ out4) {
  __shared__ __align__(16) u8 smem[131072];
  const int t = threadIdx.x;
  const int lane = t & 63, wave = t >> 6;
  const int wr = (wave >> 2) << 7;
  const int wc = (wave & 3) << 6;
  const int orig = blockIdx.x + (blockIdx.y << 3) + (blockIdx.z << 5);
  const int bidz = orig & 7;
  const int rr = orig >> 3;
  const int bidx = rr & 7, bidy = rr >> 3;
  const int bm = bidx << 8, bn = bidy << 8;
  const int kbeg = bidz << 10;           // 1024 u8 per z-slice
  float* pout = ((bidz < 4) ? out0 : out4) + (size_t)(bidz & 3) * VH;
  i32x4 acc[8][4] = {};
  const int sr = t >> 2;
  const int sc = (((t & 3) ^ ((t >> 3) & 3)) << 4);    // 16B granule (bytes)
  const u8* Ag  = A  + (size_t)(bm + sr) * Bn + sc;
  const u8* Ag2 = Ag + (size_t)128 * Bn;
  const u8* Bg  = Bm + (size_t)(bn + sr) * Bn + sc;
  const u8* Bg2 = Bg + (size_t)128 * Bn;
  const int fr = lane & 15, fg = lane >> 4;
  const int ga = ((fg ^ ((fr >> 1) & 3)) << 4);        // bytes

  auto stageA = [&](int kt) {
    u8* ad = smem + (kt & 3) * 16384 + wave * 1024;
    gload16(Ag + kbeg + (kt << 6), ad);
    gload16(Ag2 + kbeg + (kt << 6), ad + 8192);
  };
  auto stageB = [&](int kt) {
    u8* bd = smem + 65536 + (kt & 3) * 16384 + wave * 1024;
    gload16(Bg + kbeg + (kt << 6), bd);
    gload16(Bg2 + kbeg + (kt << 6), bd + 8192);
  };

  constexpr int NT = 16;
  stageA(0); stageB(0); stageA(1); stageB(1); stageA(2); stageB(2);
  asm volatile("s_waitcnt vmcnt(8)" ::: "memory");
  __builtin_amdgcn_s_barrier();
  asm volatile("" ::: "memory");
  i32x4 bf[4], af[4];
  for (int kt = 0; kt < NT; ++kt) {
    const u8* Ab = smem + (kt & 3) * 16384;
    const u8* Bb = smem + 65536 + (kt & 3) * 16384;
    const bool st = (kt < NT - 3);
    // phase A
#pragma unroll
    for (int n = 0; n < 4; ++n)
      bf[n] = *(const i32x4*)&Bb[(wc + n * 16 + fr) * 64 + ga];
#pragma unroll
    for (int m = 0; m < 4; ++m)
      af[m] = *(const i32x4*)&Ab[(wr + m * 16 + fr) * 64 + ga];
    if (st) stageA(kt + 3);
    __builtin_amdgcn_s_barrier();
    asm volatile("" ::: "memory");
    __builtin_amdgcn_s_setprio(1);
#pragma unroll
    for (int m = 0; m < 4; ++m)
#pragma unroll
      for (int n = 0; n < 4; ++n)
        acc[m][n] = __builtin_amdgcn_mfma_i32_16x16x64_i8(af[m], bf[n], acc[m][n], 0, 0, 0);
    __builtin_amdgcn_s_setprio(0);
    // phase B
#pragma unroll
    for (int m = 0; m < 4; ++m)
      af[m] = *(const i32x4*)&Ab[(wr + (m + 4) * 16 + fr) * 64 + ga];
    if (st) stageB(kt + 3);
    if (kt < NT - 3) {
      asm volatile("s_waitcnt vmcnt(8)" ::: "memory");
    } else if (kt == NT - 3) {
      asm volatile("s_waitcnt vmcnt(4)" ::: "memory");
    } else if (kt == NT - 2) {
      asm volatile("s_waitcnt vmcnt(0)" ::: "memory");
    }
    __builtin_amdgcn_s_barrier();
    asm volatile("" ::: "memory");
    __builtin_amdgcn_s_setprio(1);
#pragma unroll
    for (int m = 0; m < 4; ++m)
#pragma unroll
      for (int n = 0; n < 4; ++n)
        acc[m + 4][n] = __builtin_amdgcn_mfma_i32_16x16x64_i8(af[m], bf[n], acc[m + 4][n], 0, 0, 0);
    __builtin_amdgcn_s_setprio(0);
  }

  const int fq = lane >> 4;
#pragma unroll
  for (int m = 0; m < 8; ++m)
#pragma unroll
    for (int n = 0; n < 4; ++n)
#pragma unroll
      for (int j = 0; j < 4; ++j) {
        int rl = wr + m * 16 + fq * 4 + j;
        int cl = wc + n * 16 + fr;
        pout[(size_t)(bm + rl) * Hn + bn + cl] = (float)acc[m][n][j];
      }
}

// ---------------- merged G2+G3 (512 blocks, one launch) -------------------
// flat < 256:  G2 recon. A=h_p[B,H], B=w_cat hi, K=1024, NC=2048;
//              epilogue: sigmoid + |v_hi - vp| partial -> redp2[bidy*32+bidx].
// flat >= 256: G3 grad. A=vT+z*1024, B=hT+z*1024 (ld=Bn), K=1024, NC=1024;
//              z-slice XCD swizzle (flat%8 preserved: 256 == 0 mod 8).
__global__ __launch_bounds__(512) void g23_k(
    const u16* __restrict__ A2, const u16* __restrict__ B2,
    const u16* __restrict__ aux16, const float* __restrict__ bias2,
    float* __restrict__ redp2,
    const u16* __restrict__ A3, const u16* __restrict__ B3,
    float* __restrict__ out30, float* __restrict__ out34) {
  __shared__ __align__(16) u16 smem[65536];
  const int t = threadIdx.x;
  const int lane = t & 63, wave = t >> 6;
  const int wr = (wave >> 2) << 7;
  const int wc = (wave & 3) << 6;
  const int flat = blockIdx.x;
  const bool isG2 = (flat < 256);
  int bidx, bidy, bidz = 0;
  const u16 *Abase, *Bbase;
  int lda, ldb;
  if (isG2) {
    bidx = flat & 31; bidy = flat >> 5;
    Abase = A2; Bbase = B2; lda = Hn; ldb = 2 * Hn;
  } else {
    const int orig = flat - 256;
    bidz = orig & 7;
    const int rr = orig >> 3;          // 0..31 rank within XCD
    bidx = rr & 7; bidy = rr >> 3;
    Abase = A3 + (size_t)bidz * 1024;
    Bbase = B3 + (size_t)bidz * 1024;
    lda = Bn; ldb = Bn;
  }
  const int bm = bidx << 8, bn = bidy << 8;
  f32x4 acc[8][4] = {};
  const int sr = t >> 2;
  const int sc = (((t & 3) ^ ((t >> 3) & 3)) << 3);
  const u16* Ag  = Abase + (size_t)(bm + sr) * lda + sc;
  const u16* Ag2 = Ag + (size_t)128 * lda;
  const u16* Bg  = Bbase + (size_t)(bn + sr) * ldb + sc;
  const u16* Bg2 = Bg + (size_t)128 * ldb;
  const int fr = lane & 15, fg = lane >> 4;
  const int ga = ((fg ^ ((fr >> 1) & 3)) << 3);

  auto stageA = [&](int kt) {
    u16* ad = smem + (kt & 3) * 8192 + wave * 512;
    gload16(Ag + (kt << 5), ad);
    gload16(Ag2 + (kt << 5), ad + 4096);
  };
  auto stageB = [&](int kt) {
    u16* bd = smem + 32768 + (kt & 3) * 8192 + wave * 512;
    gload16(Bg + (kt << 5), bd);
    gload16(Bg2 + (kt << 5), bd + 4096);
  };
  auto pfl2 = [&](int ci) -> unsigned {
    const int L = (ci << 9) + t;         // 0..1023
    return (unsigned)aux16[(size_t)(bm + (L >> 2)) * 4096 + bn + ((L & 3) << 6)];
  };

  constexpr int NT = 32;
  stageA(0); stageB(0); stageA(1); stageB(1); stageA(2); stageB(2);
  asm volatile("s_waitcnt vmcnt(8)" ::: "memory");
  __builtin_amdgcn_s_barrier();
  asm volatile("" ::: "memory");
  s16x8 bf[4], af[4];
  for (int kt = 0; kt < NT; ++kt) {
    const int pb = kt & 3;
    const u16* Ab = smem + pb * 8192;
    const u16* Bb = smem + 32768 + pb * 8192;
    const bool st = (kt < NT - 3);
    // phase A
#pragma unroll
    for (int n = 0; n < 4; ++n)
      bf[n] = *(const s16x8*)&Bb[(wc + n * 16 + fr) * 32 + ga];
#pragma unroll
    for (int m = 0; m < 4; ++m)
      af[m] = *(const s16x8*)&Ab[(wr + m * 16 + fr) * 32 + ga];
    if (st) stageA(kt + 3);
    if (isG2 && kt >= NT - 8 && kt < NT - 6) {
      unsigned pfv = pfl2(kt - (NT - 8));
      asm volatile("" :: "v"(pfv));
    }
    __builtin_amdgcn_s_barrier();
    asm volatile("" ::: "memory");
    __builtin_amdgcn_s_setprio(1);
#pragma unroll
    for (int m = 0; m < 4; ++m)
#pragma unroll
      for (int n = 0; n < 4; ++n)
        acc[m][n] = __builtin_amdgcn_mfma_f32_16x16x32_bf16(af[m], bf[n], acc[m][n], 0, 0, 0);
    __builtin_amdgcn_s_setprio(0);
    // phase B
#pragma unroll
    for (int m = 0; m < 4; ++m)
      af[m] = *(const s16x8*)&Ab[(wr + (m + 4) * 16 + fr) * 32 + ga];
    if (st) stageB(kt + 3);
    if (kt < NT - 3) {
      asm volatile("s_waitcnt vmcnt(8)" ::: "memory");
    } else if (kt == NT - 3) {
      asm volatile("s_waitcnt vmcnt(4)" ::: "memory");
    } else if (kt == NT - 2) {
      asm volatile("s_waitcnt vmcnt(0)" ::: "memory");
    }
    __builtin_amdgcn_s_barrier();
    asm volatile("" ::: "memory");
    __builtin_amdgcn_s_setprio(1);
#pragma unroll
    for (int m = 0; m < 4; ++m)
#pragma unroll
      for (int n = 0; n < 4; ++n)
        acc[m + 4][n] = __builtin_amdgcn_mfma_f32_16x16x32_bf16(af[m], bf[n], acc[m + 4][n], 0, 0, 0);
    __builtin_amdgcn_s_setprio(0);
  }

  const int fq = lane >> 4;
  if (isG2) {
    // pipelined recon vs v_cat-hi (u16, stride 4096), depth-8 window (&7).
    float bcol[4];
#pragma unroll
    for (int n = 0; n < 4; ++n) bcol[n] = bias2[bn + wc + n * 16 + fr];
    const size_t ebase = (size_t)(bm + wr + fq * 4) * 4096 + (bn + wc + fr);
    float ax[8][4];
    auto ld4 = [&](int ci, float* dst) {
      size_t e0 = ebase + (size_t)((ci >> 2) << 4) * 4096 + ((ci & 3) << 4);
      dst[0] = bf2f(aux16[e0]);            dst[1] = bf2f(aux16[e0 + 4096]);
      dst[2] = bf2f(aux16[e0 + 2 * 4096]); dst[3] = bf2f(aux16[e0 + 3 * 4096]);
    };
#pragma unroll
    for (int ci = 0; ci < 8; ++ci) ld4(ci, ax[ci]);
#pragma unroll
    for (int m = 0; m < 8; ++m)
#pragma unroll
      for (int n = 0; n < 4; ++n)
#pragma unroll
        for (int j = 0; j < 4; ++j)
          acc[m][n][j] = sigmoidf_(acc[m][n][j] + bcol[n]);
    float lsum = 0.f;
#pragma unroll
    for (int ci = 0; ci < 32; ++ci) {
      const int m = ci >> 2, n = ci & 3;
#pragma unroll
      for (int j = 0; j < 4; ++j) lsum += fabsf(ax[ci & 7][j] - acc[m][n][j]);
      if (ci < 24) ld4(ci + 8, ax[ci & 7]);
    }
#pragma unroll
    for (int off = 32; off > 0; off >>= 1) lsum += __shfl_down(lsum, off);
    __syncthreads();
    float* redlds = (float*)smem;
    if (lane == 0) redlds[wave] = lsum;
    __syncthreads();
    if (t == 0) {
      float s = 0.f;
#pragma unroll
      for (int wv = 0; wv < 8; ++wv) s += redlds[wv];
      redp2[(size_t)bidy * 32 + bidx] = s;
    }
  } else {
    float* pout = ((bidz < 4) ? out30 : out34) + (size_t)(bidz & 3) * VH;
#pragma unroll
    for (int m = 0; m < 8; ++m)
#pragma unroll
      for (int n = 0; n < 4; ++n)
#pragma unroll
        for (int j = 0; j < 4; ++j) {
          int rl = wr + m * 16 + fq * 4 + j;
          int cl = wc + n * 16 + fr;
          pout[(size_t)(bm + rl) * Hn + bn + cl] = acc[m][n][j];
        }
  }
}

// out[i] = sum_{z<8} p[z][i]  (scalar stores: out base misaligned)
__global__ void reduce8_k(const float* __restrict__ p, float* __restrict__ out) {
  size_t e = ((size_t)blockIdx.x * 256 + threadIdx.x) * 4;
  f32x4 r = {};
#pragma unroll
  for (int z = 0; z < 8; ++z) r += *(const f32x4*)&p[(size_t)z * VH + e];
  out[e + 0] = r[0]; out[e + 1] = r[1]; out[e + 2] = r[2]; out[e + 3] = r[3];
}

// merged tail: blocks <2048 = reduce8s (w_grad = model partials - data grad),
// blocks >=2048 (8) = finalize (bias grads + recon scalar).
__global__ void tail_k(const float* __restrict__ pa, const float* __restrict__ pb,
                       const float* __restrict__ sums, float* __restrict__ out) {
  const int b = blockIdx.x;
  float* outw = out + OUT_WGRAD;
  if (b < 2048) {
    size_t e = ((size_t)b * 256 + threadIdx.x) * 4;
    f32x4 r = {};
#pragma unroll
    for (int z = 0; z < 4; ++z) r += *(const f32x4*)&pa[(size_t)z * VH + e];
#pragma unroll
    for (int z = 0; z < 4; ++z) r += *(const f32x4*)&pb[(size_t)z * VH + e];
    float s0 = outw[e + 0], s1 = outw[e + 1], s2 = outw[e + 2], s3 = outw[e + 3];
    outw[e + 0] = r[0] - s0; outw[e + 1] = r[1] - s1;
    outw[e + 2] = r[2] - s2; outw[e + 3] = r[3] - s3;
  } else {
    const int i = (b - 2048) * 256 + threadIdx.x;   // 0..2047
    const float* recon_p = sums;                 // 256
    const float* vbd = sums + 1024;              // 128 x 2048
    const float* hbd = vbd + 128 * 2048;         // 128 x 1024
    const float* vbm = hbd + 128 * 1024;         // 64 x 2048
    const float* hbm = vbm + 128 * 2048;         // 128 x 1024
    if (i < 2048) {
      float d = 0.f, m = 0.f;
      for (int k = 0; k < 128; ++k) d += vbd[k * 2048 + i];
      for (int k = 0; k < 64; ++k)  m += vbm[k * 2048 + i];
      out[OUT_VBG + i] = m - d;
    }
    if (i < 1024) {
      float d = 0.f, m = 0.f;
      for (int k = 0; k < 128; ++k) { d += hbd[k * 1024 + i]; m += hbm[k * 1024 + i]; }
      out[OUT_HBG + i] = m - d;
    }
    if (i == 0) {
      float s = 0.f;
      for (int k = 0; k < 256; ++k) s += recon_p[k];
      out[OUT_RECON] = s * (1.0f / 16777216.0f);  // /(B*V)
    }
  }
}

extern "C" void kernel_launch(void* const* d_in, const int* in_sizes, int n_in,
                              void* d_out, int out_size, void* d_ws, size_t ws_size,
                              hipStream_t stream) {
  (void)in_sizes; (void)n_in; (void)out_size;
  const float* v   = (const float*)d_in[0];
  const float* w   = (const float*)d_in[1];
  const float* vb  = (const float*)d_in[2];
  const float* hb  = (const float*)d_in[3];
  const float* u_h = (const float*)d_in[4];
  const float* u_v = (const float*)d_in[5];
  float* out = (float*)d_out;
  char* ws = (char*)d_ws;
  if (ws_size < 204734464ULL) return;

  float* sums    = (float*)ws;               // 3.25 MiB region
  float* recon_p = sums;                     // 256
  float* vbd_p   = sums + 1024;              // 128*2048
  float* hbd_p   = vbd_p + 128 * 2048;       // 128*1024
  float* vbm_p   = hbd_p + 128 * 1024;       // 64*2048
  float* hbm_p   = vbm_p + 128 * 2048;       // 128*1024
  char* p = ws + 3407872;
  u16* v_cat  = (u16*)p;  p += (size_t)Bn * 2 * Vn * 2;   // 64 MiB [B,2V]
  u16* wT_cat = (u16*)p;  p += (size_t)Hn * 2 * Vn * 2;   // 8 MiB [H,2V]
  u16* w_cat  = (u16*)p;  p += (size_t)Vn * 2 * Hn * 2;   // 8 MiB [V,2H]
  u16* h_p    = (u16*)p;  p += BH * 2;                    // 16 MiB [B,H]
  u16* hbin   = (u16*)p;  p += BH * 2;                    // 16 MiB [B,H]
  u16* vT     = (u16*)p;  p += (size_t)Vn * Bn * 2;       // 32 MiB [V,B]
  u16* hT     = (u16*)p;  p += (size_t)Hn * Bn * 2;       // 16 MiB [H,B]
  float* big  = (float*)p;                                // 32 MiB time-shared
  u16* vk   = v_cat;            // v_cat dead after g23 (G3 partials overwrite)
  u8*  vkT8 = (u8*)vT;          // vT dead after g23; u8 vkT (16 MiB used)
  u8*  h2T8 = (u8*)hT;          // hT dead after g23; u8 h2T (8 MiB used)
  float* vcat_f = (float*)v_cat;   // 64 MiB: G3's 8 partials
  float* hpbuf  = (float*)h_p;     // h_p+hbin region (32 MiB) as f32 partials
  float* outW   = out + OUT_WGRAD;

  prep_all_k<<<4608, 256, 0, stream>>>(v, v_cat, vT, vbd_p, w, w_cat, wT_cat);
  // G1a: split-K x2 partials (z0 -> out[0..BH) scratch, z1 -> big)
  gemm256<1><<<dim3(32, 4, 2), 512, 0, stream>>>(
      v_cat, 2 * Vn, wT_cat, 2 * Vn, 3072, nullptr, nullptr, nullptr,
      out, nullptr, nullptr, big, nullptr, nullptr);
  // epi: h_pred / h_p / hbin / hT / hbd
  epi_h_k<1><<<dim3(128, 16), 256, 0, stream>>>(
      out, big, hb, u_h, out, h_p, hbin, hT, hbd_p);
  // merged G2 (recon) + G3 (w_data_grad partials): 512 blocks, one launch
  g23_k<<<512, 512, 0, stream>>>(
      h_p, w_cat, v_cat, vb, recon_p,
      vT, hT, vcat_f, vcat_f + 4 * VH);
  reduce8_k<<<2048, 256, 0, stream>>>(vcat_f, outW);   // outW = data-grad sum
  // G4: vk/vkT(u8) + vbm partials (fused sample+transpose epilogue)
  gemm256<4><<<dim3(32, 8), 512, 0, stream>>>(
      hbin, Hn, w_cat, 2 * Hn, 2 * Hn, vb, u_v, nullptr,
      nullptr, vk, nullptr, nullptr, (u16*)vkT8, vbm_p);
  // G5a: split-K x2 partials (z0 -> hpbuf, z1 -> big); h_p/hbin dead now
  gemm256<5><<<dim3(32, 4, 2), 512, 0, stream>>>(
      vk, Vn, wT_cat, 2 * Vn, 2048, nullptr, nullptr, nullptr,
      hpbuf, nullptr, nullptr, big, nullptr, nullptr);
  // epi: h2T (u8) + hbm
  epi_h_k<5><<<dim3(128, 16), 256, 0, stream>>>(
      hpbuf, big, hb, u_h + BH, nullptr, nullptr, nullptr, (u16*)h2T8, hbm_p);
  // G6: w_model_grad partials via i8 MFMA (exact; split-K x8: z<4 -> hpbuf,
  // z>=4 -> big)
  gemm_i8_k<<<dim3(8, 4, 8), 512, 0, stream>>>(vkT8, h2T8, hpbuf, big);
  // merged reduce8s + finalize
  tail_k<<<2056, 256, 0, stream>>>(hpbuf, big, sums, out);
}